// Round 1
// 4377.361 us; speedup vs baseline: 2.3024x; 2.3024x over previous
//
#include <hip/hip_runtime.h>

#define SEQ 2048
#define DM  1024
#define NH  16
#define HDIM 64

typedef __bf16 bf16x8 __attribute__((ext_vector_type(8)));
typedef float  f32x4  __attribute__((ext_vector_type(4)));

// ---------------------------------------------------------------- decay LUT
__global__ void decay_kernel(float* __restrict__ lut) {
    int i = blockIdx.x * 256 + threadIdx.x;
    if (i < SEQ) lut[i] = expf(-0.1f * (float)i);
}

// ------------------------------------------------ sentinel: zero the output
__global__ void zero_out(float* __restrict__ out, int n) {
    int i = blockIdx.x * 256 + threadIdx.x;
    if (i < n) out[i] = 0.f;
}

// ------------------------------------------------ fp32 -> bf16 (8 elems/thr)
__global__ __launch_bounds__(256) void cvt_bf16(
    const float* __restrict__ src, __bf16* __restrict__ dst, int n8)
{
    int i = blockIdx.x * 256 + threadIdx.x;
    if (i >= n8) return;
    const float4* s = reinterpret_cast<const float4*>(src) + (size_t)i * 2;
    float4 x = s[0], y = s[1];
    bf16x8 o;
    o[0] = (__bf16)x.x; o[1] = (__bf16)x.y; o[2] = (__bf16)x.z; o[3] = (__bf16)x.w;
    o[4] = (__bf16)y.x; o[5] = (__bf16)y.y; o[6] = (__bf16)y.z; o[7] = (__bf16)y.w;
    reinterpret_cast<bf16x8*>(dst)[i] = o;
}

// ---------------------------------------------------------------- MFMA GEMM
// C[m][n] = sum_k A[m][k] * W[n][k] + bias[n]   (B^T layout: both K-contig)
// A: [2048][1024] bf16, W: [1024][1024] bf16. 128x128 tile, BK=32, 4 waves.
// mode 0: bf16 store; mode 1: f32 store; mode 2: f32 store + resid add.
struct GemmBatch {
    const __bf16* A;
    const __bf16* W[3];
    const float*  bias[3];
    void*         out[3];
    int           mode[3];
    const float*  resid;
};

// chunk-column swizzle: spreads the 4x16B chunks of each 64B LDS row so that
// fragment ds_read_b128 (16 lanes, rows 0..15, same chunk col) is ~2-way.
__device__ __forceinline__ int swz4(int r) { return (r ^ (r >> 2)) & 3; }

__global__ __launch_bounds__(256) void gemm_bt(GemmBatch g) {
    const int z = blockIdx.z;
    const __bf16* __restrict__ A = g.A;
    const __bf16* __restrict__ W = g.W[z];
    const int ncol0 = blockIdx.x * 128;
    const int mrow0 = blockIdx.y * 128;
    const int tid = threadIdx.x, lane = tid & 63, wv = tid >> 6;
    const int wm = wv >> 1, wn = wv & 1;          // 2x2 wave grid, 64x64 each
    const int fr = lane & 15, fj = lane >> 4;     // fragment row / k-chunk

    __shared__ __bf16 As[128 * 32];
    __shared__ __bf16 Bs[128 * 32];

    f32x4 acc[4][4];
#pragma unroll
    for (int i = 0; i < 4; ++i)
#pragma unroll
        for (int j = 0; j < 4; ++j)
#pragma unroll
            for (int e = 0; e < 4; ++e) acc[i][j][e] = 0.f;

    // staging: 512 chunks of 8 bf16; thread t owns chunks t and t+256
    const int c0 = tid, c1 = tid + 256;
    const int r0 = c0 >> 2, j0 = c0 & 3;
    const int r1 = c1 >> 2, j1 = c1 & 3;
    const int la0 = r0 * 32 + ((j0 ^ swz4(r0)) << 3);
    const int la1 = r1 * 32 + ((j1 ^ swz4(r1)) << 3);

    const __bf16* Ap0 = A + (size_t)(mrow0 + r0) * DM + j0 * 8;
    const __bf16* Ap1 = A + (size_t)(mrow0 + r1) * DM + j1 * 8;
    const __bf16* Wp0 = W + (size_t)(ncol0 + r0) * DM + j0 * 8;
    const __bf16* Wp1 = W + (size_t)(ncol0 + r1) * DM + j1 * 8;

    bf16x8 ra0 = *(const bf16x8*)(Ap0);
    bf16x8 ra1 = *(const bf16x8*)(Ap1);
    bf16x8 rb0 = *(const bf16x8*)(Wp0);
    bf16x8 rb1 = *(const bf16x8*)(Wp1);

    for (int kt = 0; kt < DM; kt += 32) {
        __syncthreads();                          // prev-iter LDS reads done
        *(bf16x8*)(As + la0) = ra0;
        *(bf16x8*)(As + la1) = ra1;
        *(bf16x8*)(Bs + la0) = rb0;
        *(bf16x8*)(Bs + la1) = rb1;
        __syncthreads();
        if (kt + 32 < DM) {                       // prefetch next K-tile
            ra0 = *(const bf16x8*)(Ap0 + kt + 32);
            ra1 = *(const bf16x8*)(Ap1 + kt + 32);
            rb0 = *(const bf16x8*)(Wp0 + kt + 32);
            rb1 = *(const bf16x8*)(Wp1 + kt + 32);
        }
        bf16x8 af[4], bfv[4];
#pragma unroll
        for (int mf = 0; mf < 4; ++mf) {
            int r = wm * 64 + mf * 16 + fr;
            af[mf] = *(const bf16x8*)(As + r * 32 + ((fj ^ swz4(r)) << 3));
        }
#pragma unroll
        for (int nf = 0; nf < 4; ++nf) {
            int r = wn * 64 + nf * 16 + fr;
            bfv[nf] = *(const bf16x8*)(Bs + r * 32 + ((fj ^ swz4(r)) << 3));
        }
#pragma unroll
        for (int mf = 0; mf < 4; ++mf)
#pragma unroll
            for (int nf = 0; nf < 4; ++nf)
                acc[mf][nf] = __builtin_amdgcn_mfma_f32_16x16x32_bf16(
                    af[mf], bfv[nf], acc[mf][nf], 0, 0, 0);
    }

    // epilogue: C/D layout col=lane&15, row=(lane>>4)*4+reg  [verified m89]
    const int mode = g.mode[z];
    const float* __restrict__ bias = g.bias[z];
#pragma unroll
    for (int mf = 0; mf < 4; ++mf) {
#pragma unroll
        for (int nf = 0; nf < 4; ++nf) {
            const int col = ncol0 + wn * 64 + nf * 16 + fr;
            const int rw0 = mrow0 + wm * 64 + mf * 16 + fj * 4;
            const float bc = bias[col];
#pragma unroll
            for (int jj = 0; jj < 4; ++jj) {
                float vv = acc[mf][nf][jj] + bc;
                const size_t idx = (size_t)(rw0 + jj) * DM + col;
                if (mode == 0) {
                    ((__bf16*)g.out[z])[idx] = (__bf16)vv;
                } else {
                    if (mode == 2) vv += g.resid[idx];
                    ((float*)g.out[z])[idx] = vv;
                }
            }
        }
    }
}

// ------------------------------------- amplitudes / phases, 16 lanes/head
__global__ __launch_bounds__(256) void amp_fast(
    const float* __restrict__ hs,
    const float* __restrict__ amp_w, const float* __restrict__ amp_b,
    const float* __restrict__ ph_w,  const float* __restrict__ ph_b,
    float* __restrict__ cA, float* __restrict__ sA)
{
    const int s = blockIdx.x;
    __shared__ float hrow[DM];
    for (int i = threadIdx.x; i < DM; i += 256)
        hrow[i] = hs[(size_t)s * DM + i];
    __syncthreads();
    const int h = threadIdx.x >> 4, sub = threadIdx.x & 15;
    const float* aw = amp_w + (size_t)h * DM;
    const float* pw = ph_w  + (size_t)h * DM;
    float da = 0.f, dp = 0.f;
    for (int k = sub; k < DM; k += 16) {
        const float hv = hrow[k];
        da += hv * aw[k];
        dp += hv * pw[k];
    }
#pragma unroll
    for (int off = 8; off >= 1; off >>= 1) {
        da += __shfl_xor(da, off);
        dp += __shfl_xor(dp, off);
    }
    if (sub == 0) {
        da += amp_b[h]; dp += ph_b[h];
        float amp = 1.f / (1.f + expf(-da));
        float ph  = tanhf(dp) * 3.14159265358979323846f;
        cA[s * NH + h] = 0.3f * amp * cosf(ph);
        sA[s * NH + h] = 0.3f * amp * sinf(ph);
    }
}

// ------------------------------------- naive mixer -> mixedT[h*64+o][s]
__global__ __launch_bounds__(64) void mixer_naive(
    const __bf16* __restrict__ v, const float* __restrict__ mix_w,
    const float* __restrict__ mix_b,
    const float* __restrict__ cA, const float* __restrict__ sA,
    __bf16* __restrict__ mixedT)
{
    const int s = blockIdx.x, h = blockIdx.y, o = threadIdx.x;  // 64 threads
    __shared__ float vrow[HDIM], sup[HDIM];
    vrow[o] = (float)v[(size_t)s * DM + h * HDIM + o];
    __syncthreads();
    float acc = mix_b[h * HDIM + o];
    const float* wr = mix_w + (size_t)h * HDIM * HDIM + o * HDIM;
    for (int d = 0; d < HDIM; ++d) acc += vrow[d] * wr[d];
    sup[o] = acc;
    __syncthreads();
    const float ca = cA[s * NH + h], sa = sA[s * NH + h];
    const float mval = vrow[o] + ca * sup[o] + sa * sup[(o + 63) & 63];
    mixedT[(size_t)(h * HDIM + o) * SEQ + s] = (__bf16)mval;
}

// ------------------- brute-force attention; q/k fp32, eq/ek bf16 (block s,h)
__global__ __launch_bounds__(256) void attn_f32(
    const float* __restrict__ q, const float* __restrict__ k,
    const __bf16* __restrict__ eq, const __bf16* __restrict__ ek,
    const __bf16* __restrict__ mixedT, const float* __restrict__ lutg,
    __bf16* __restrict__ ctx)
{
    const int s = blockIdx.x, h = blockIdx.y;
    const int tid = threadIdx.x, wave = tid >> 6, lane = tid & 63;

    __shared__ float logit[SEQ];
    __shared__ float qrow[HDIM], eqrow[HDIM];
    __shared__ float red[8];
    __shared__ float part[4][HDIM];

    if (tid < 64)       qrow[tid]       = q [(size_t)s * DM + h * HDIM + tid];
    else if (tid < 128) eqrow[tid - 64] = (float)eq[(size_t)s * DM + h * HDIM + tid - 64];
    __syncthreads();

    float lm = -1e30f;
    for (int key = tid; key < SEQ; key += 256) {
        const float4*  kr = reinterpret_cast<const float4*>(k + (size_t)key * DM + h * HDIM);
        const bf16x8*  er = reinterpret_cast<const bf16x8*>(ek + (size_t)key * DM + h * HDIM);
        float dq = 0.f, de = 0.f;
#pragma unroll
        for (int i = 0; i < 16; ++i) {
            float4 kv = kr[i];
            dq += qrow[4*i] * kv.x + qrow[4*i+1] * kv.y
                + qrow[4*i+2] * kv.z + qrow[4*i+3] * kv.w;
        }
#pragma unroll
        for (int i = 0; i < 8; ++i) {
            bf16x8 ev = er[i];
#pragma unroll
            for (int e = 0; e < 8; ++e) de += eqrow[8*i + e] * (float)ev[e];
        }
        int dd = s - key; dd = dd < 0 ? -dd : dd;
        float lg = 0.125f * dq + 0.0625f * de * lutg[dd];
        logit[key] = lg;
        lm = fmaxf(lm, lg);
    }
#pragma unroll
    for (int off = 32; off >= 1; off >>= 1) lm = fmaxf(lm, __shfl_xor(lm, off));
    if (lane == 0) red[wave] = lm;
    __syncthreads();
    const float mx = fmaxf(fmaxf(red[0], red[1]), fmaxf(red[2], red[3]));

    float ls = 0.f;
    for (int key = tid; key < SEQ; key += 256) {
        float p = expf(logit[key] - mx);
        logit[key] = p;
        ls += p;
    }
#pragma unroll
    for (int off = 32; off >= 1; off >>= 1) ls += __shfl_xor(ls, off);
    if (lane == 0) red[4 + wave] = ls;
    __syncthreads();
    const float denom = red[4] + red[5] + red[6] + red[7];

    const int d = tid & 63, g = tid >> 6;
    const __bf16* mrow = mixedT + (size_t)(h * HDIM + d) * SEQ;
    float acc = 0.f;
    for (int key = g * 512; key < (g + 1) * 512; key += 8) {
        bf16x8 mv = *reinterpret_cast<const bf16x8*>(mrow + key);
#pragma unroll
        for (int e = 0; e < 8; ++e) acc += logit[key + e] * (float)mv[e];
    }
    part[g][d] = acc;
    __syncthreads();
    if (tid < 64) {
        float val = (part[0][tid] + part[1][tid] + part[2][tid] + part[3][tid]) / denom;
        ctx[(size_t)s * DM + h * HDIM + tid] = (__bf16)val;
    }
}

// --------------------------------------------- layer norm, FP32 OUTPUT
__global__ __launch_bounds__(256) void lnorm_f32(
    const float* __restrict__ res, const float* __restrict__ g,
    const float* __restrict__ b, float* __restrict__ out)
{
    const int row = blockIdx.x, tid = threadIdx.x;
    const int wave = tid >> 6, lane = tid & 63;
    __shared__ float red[8];
    const float4 x = reinterpret_cast<const float4*>(res + (size_t)row * DM)[tid];
    float s  = x.x + x.y + x.z + x.w;
    float s2 = x.x * x.x + x.y * x.y + x.z * x.z + x.w * x.w;
#pragma unroll
    for (int off = 32; off >= 1; off >>= 1) {
        s  += __shfl_xor(s, off);
        s2 += __shfl_xor(s2, off);
    }
    if (lane == 0) { red[wave] = s; red[4 + wave] = s2; }
    __syncthreads();
    s  = red[0] + red[1] + red[2] + red[3];
    s2 = red[4] + red[5] + red[6] + red[7];
    const float mu  = s * (1.f / DM);
    const float var = s2 * (1.f / DM) - mu * mu;
    const float inv = rsqrtf(var + 1e-5f);
    const int col = tid * 4;
    float4 o;
    o.x = (x.x - mu) * inv * g[col + 0] + b[col + 0];
    o.y = (x.y - mu) * inv * g[col + 1] + b[col + 1];
    o.z = (x.z - mu) * inv * g[col + 2] + b[col + 2];
    o.w = (x.w - mu) * inv * g[col + 3] + b[col + 3];
    reinterpret_cast<float4*>(out + (size_t)row * DM)[tid] = o;
}

// ---------------------------------------------------------------- launch
// OUTPUT IS FP32. Score-critical path kept fp32 (q/k stored fp32; only the
// MFMA input rounding of hs/W is new). eq/ek bf16 (esc term is tiny).
// ws layout (~34.3 MB, under the proven 36.3 MB budget):
//   [0,4M)   hsb (bf16 hs)          -> overlaid by mixedT after proj GEMMs
//   [4,10M)  3-slot rotating bf16 weight buffer (Wq/Wk/Wv, then Weq/Wek, Wo)
//   [10,18M) q fp32                 -> overlaid by res after attn
//   [18,26M) k fp32
//   [26,30M) eq bf16   [30,34M) ek bf16   [34M..) cA/sA/lut
// v (bf16) and ctx (bf16) staged in d_out (v dead before ctx written; lnorm
// rewrites the full 8 MB fp32 at the end).
extern "C" void kernel_launch(void* const* d_in, const int* in_sizes, int n_in,
                              void* d_out, int out_size, void* d_ws, size_t ws_size,
                              hipStream_t stream) {
    const float* hs   = (const float*)d_in[0];
    const float* Wq   = (const float*)d_in[1];
    const float* bq   = (const float*)d_in[2];
    const float* Wk   = (const float*)d_in[3];
    const float* bk   = (const float*)d_in[4];
    const float* Wv   = (const float*)d_in[5];
    const float* bv   = (const float*)d_in[6];
    const float* Wo   = (const float*)d_in[7];
    const float* bo   = (const float*)d_in[8];
    const float* Weq  = (const float*)d_in[9];
    const float* beq  = (const float*)d_in[10];
    const float* Wek  = (const float*)d_in[11];
    const float* bek  = (const float*)d_in[12];
    const float* ampw = (const float*)d_in[13];
    const float* ampb = (const float*)d_in[14];
    const float* phw  = (const float*)d_in[15];
    const float* phb  = (const float*)d_in[16];
    const float* mixw = (const float*)d_in[17];
    const float* mixb = (const float*)d_in[18];
    const float* lng  = (const float*)d_in[19];
    const float* lnb  = (const float*)d_in[20];
    float* out = (float*)d_out;

    static const int expect[21] = {
        2097152, 1048576, 1024, 1048576, 1024, 1048576, 1024, 1048576, 1024,
        1048576, 1024, 1048576, 1024, 16384, 16, 16384, 16, 65536, 1024,
        1024, 1024};
    bool ok = (n_in == 21) && (out_size == 2097152);
    if (ok) for (int i = 0; i < 21; ++i) ok = ok && (in_sizes[i] == expect[i]);
    if (!ok) {
        zero_out<<<(out_size + 255) / 256, 256, 0, stream>>>(out, out_size);
        return;
    }

    char* ws = (char*)d_ws;
    __bf16* hsb = (__bf16*)ws;
    __bf16* w0  = (__bf16*)(ws + (4  << 20));
    __bf16* w1  = (__bf16*)(ws + (6  << 20));
    __bf16* w2  = (__bf16*)(ws + (8  << 20));
    float*  qf  = (float*) (ws + (10 << 20));
    float*  kf  = (float*) (ws + (18 << 20));
    __bf16* eqb = (__bf16*)(ws + (26 << 20));
    __bf16* ekb = (__bf16*)(ws + (30 << 20));
    float*  cA  = (float*) (ws + (34 << 20));
    float*  sA  = cA + SEQ * NH;
    float*  lut = sA + SEQ * NH;
    __bf16* mxT = hsb;                    // overlay: hsb dead after proj GEMMs
    float*  res = qf;                     // overlay: q dead after attn
    __bf16* vb  = (__bf16*)d_out;
    __bf16* ctx = (__bf16*)d_out;

    decay_kernel<<<8, 256, 0, stream>>>(lut);

    const int H8 = SEQ * DM / 8;          // 262144
    const int W8 = DM * DM / 8;           // 131072
    cvt_bf16<<<(H8 + 255) / 256, 256, 0, stream>>>(hs, hsb, H8);
    cvt_bf16<<<(W8 + 255) / 256, 256, 0, stream>>>(Wq, w0, W8);
    cvt_bf16<<<(W8 + 255) / 256, 256, 0, stream>>>(Wk, w1, W8);
    cvt_bf16<<<(W8 + 255) / 256, 256, 0, stream>>>(Wv, w2, W8);

    GemmBatch g1 = {};
    g1.A = hsb;
    g1.W[0] = w0;  g1.W[1] = w1;  g1.W[2] = w2;
    g1.bias[0] = bq; g1.bias[1] = bk; g1.bias[2] = bv;
    g1.out[0] = qf;  g1.out[1] = kf;  g1.out[2] = vb;
    g1.mode[0] = 1;  g1.mode[1] = 1;  g1.mode[2] = 0;
    g1.resid = nullptr;
    gemm_bt<<<dim3(DM / 128, SEQ / 128, 3), 256, 0, stream>>>(g1);

    cvt_bf16<<<(W8 + 255) / 256, 256, 0, stream>>>(Weq, w0, W8);
    cvt_bf16<<<(W8 + 255) / 256, 256, 0, stream>>>(Wek, w1, W8);

    GemmBatch g2 = {};
    g2.A = hsb;
    g2.W[0] = w0;  g2.W[1] = w1;
    g2.bias[0] = beq; g2.bias[1] = bek;
    g2.out[0] = eqb;  g2.out[1] = ekb;
    g2.mode[0] = 0;   g2.mode[1] = 0;
    g2.resid = nullptr;
    gemm_bt<<<dim3(DM / 128, SEQ / 128, 2), 256, 0, stream>>>(g2);

    amp_fast<<<SEQ, 256, 0, stream>>>(hs, ampw, ampb, phw, phb, cA, sA);
    mixer_naive<<<dim3(SEQ, NH), 64, 0, stream>>>(vb, mixw, mixb, cA, sA, mxT);
    attn_f32<<<dim3(SEQ, NH), 256, 0, stream>>>(qf, kf, eqb, ekb, mxT, lut, ctx);

    cvt_bf16<<<(W8 + 255) / 256, 256, 0, stream>>>(Wo, w0, W8);
    GemmBatch g3 = {};
    g3.A = ctx;
    g3.W[0] = w0; g3.bias[0] = bo; g3.out[0] = res; g3.mode[0] = 2;
    g3.resid = hs;
    gemm_bt<<<dim3(DM / 128, SEQ / 128, 1), 256, 0, stream>>>(g3);

    lnorm_f32<<<SEQ, 256, 0, stream>>>(res, lng, lnb, out);
}

// Round 2
// 463.213 us; speedup vs baseline: 21.7573x; 9.4500x over previous
//
#include <hip/hip_runtime.h>

#define SEQ 2048
#define DM  1024
#define NH  16
#define HDIM 64

typedef __bf16   bf16x8 __attribute__((ext_vector_type(8)));
typedef float    f32x4  __attribute__((ext_vector_type(4)));
typedef _Float16 half8  __attribute__((ext_vector_type(8)));
typedef _Float16 half4v __attribute__((ext_vector_type(4)));

// ------------------------------------------------ sentinel: zero the output
__global__ void zero_out(float* __restrict__ out, int n) {
    int i = blockIdx.x * 256 + threadIdx.x;
    if (i < n) out[i] = 0.f;
}

// ------------------------------------------------ fp32 -> bf16 (8 elems/thr)
__global__ __launch_bounds__(256) void cvt_bf16(
    const float* __restrict__ src, __bf16* __restrict__ dst, int n8)
{
    int i = blockIdx.x * 256 + threadIdx.x;
    if (i >= n8) return;
    const float4* s = reinterpret_cast<const float4*>(src) + (size_t)i * 2;
    float4 x = s[0], y = s[1];
    bf16x8 o;
    o[0] = (__bf16)x.x; o[1] = (__bf16)x.y; o[2] = (__bf16)x.z; o[3] = (__bf16)x.w;
    o[4] = (__bf16)y.x; o[5] = (__bf16)y.y; o[6] = (__bf16)y.z; o[7] = (__bf16)y.w;
    reinterpret_cast<bf16x8*>(dst)[i] = o;
}

// ---------------------------------------------------------------- MFMA GEMM
// C[m][n] = sum_k A[m][k] * W[n][k] + bias[n]   (B^T layout: both K-contig)
// mode 0: bf16 store; mode 1: f32; mode 2: f32 + resid add; mode 3: f16.
struct GemmBatch {
    const __bf16* A;
    const __bf16* W[3];
    const float*  bias[3];
    void*         out[3];
    int           mode[3];
    const float*  resid;
};

__device__ __forceinline__ int swz4(int r) { return (r ^ (r >> 2)) & 3; }

__global__ __launch_bounds__(256) void gemm_bt(GemmBatch g) {
    const int z = blockIdx.z;
    const __bf16* __restrict__ A = g.A;
    const __bf16* __restrict__ W = g.W[z];
    const int ncol0 = blockIdx.x * 128;
    const int mrow0 = blockIdx.y * 128;
    const int tid = threadIdx.x, lane = tid & 63, wv = tid >> 6;
    const int wm = wv >> 1, wn = wv & 1;
    const int fr = lane & 15, fj = lane >> 4;

    __shared__ __bf16 As[128 * 32];
    __shared__ __bf16 Bs[128 * 32];

    f32x4 acc[4][4];
#pragma unroll
    for (int i = 0; i < 4; ++i)
#pragma unroll
        for (int j = 0; j < 4; ++j)
#pragma unroll
            for (int e = 0; e < 4; ++e) acc[i][j][e] = 0.f;

    const int c0 = tid, c1 = tid + 256;
    const int r0 = c0 >> 2, j0 = c0 & 3;
    const int r1 = c1 >> 2, j1 = c1 & 3;
    const int la0 = r0 * 32 + ((j0 ^ swz4(r0)) << 3);
    const int la1 = r1 * 32 + ((j1 ^ swz4(r1)) << 3);

    const __bf16* Ap0 = A + (size_t)(mrow0 + r0) * DM + j0 * 8;
    const __bf16* Ap1 = A + (size_t)(mrow0 + r1) * DM + j1 * 8;
    const __bf16* Wp0 = W + (size_t)(ncol0 + r0) * DM + j0 * 8;
    const __bf16* Wp1 = W + (size_t)(ncol0 + r1) * DM + j1 * 8;

    bf16x8 ra0 = *(const bf16x8*)(Ap0);
    bf16x8 ra1 = *(const bf16x8*)(Ap1);
    bf16x8 rb0 = *(const bf16x8*)(Wp0);
    bf16x8 rb1 = *(const bf16x8*)(Wp1);

    for (int kt = 0; kt < DM; kt += 32) {
        __syncthreads();
        *(bf16x8*)(As + la0) = ra0;
        *(bf16x8*)(As + la1) = ra1;
        *(bf16x8*)(Bs + la0) = rb0;
        *(bf16x8*)(Bs + la1) = rb1;
        __syncthreads();
        if (kt + 32 < DM) {
            ra0 = *(const bf16x8*)(Ap0 + kt + 32);
            ra1 = *(const bf16x8*)(Ap1 + kt + 32);
            rb0 = *(const bf16x8*)(Wp0 + kt + 32);
            rb1 = *(const bf16x8*)(Wp1 + kt + 32);
        }
        bf16x8 af[4], bfv[4];
#pragma unroll
        for (int mf = 0; mf < 4; ++mf) {
            int r = wm * 64 + mf * 16 + fr;
            af[mf] = *(const bf16x8*)(As + r * 32 + ((fj ^ swz4(r)) << 3));
        }
#pragma unroll
        for (int nf = 0; nf < 4; ++nf) {
            int r = wn * 64 + nf * 16 + fr;
            bfv[nf] = *(const bf16x8*)(Bs + r * 32 + ((fj ^ swz4(r)) << 3));
        }
#pragma unroll
        for (int mf = 0; mf < 4; ++mf)
#pragma unroll
            for (int nf = 0; nf < 4; ++nf)
                acc[mf][nf] = __builtin_amdgcn_mfma_f32_16x16x32_bf16(
                    af[mf], bfv[nf], acc[mf][nf], 0, 0, 0);
    }

    const int mode = g.mode[z];
    const float* __restrict__ bias = g.bias[z];
#pragma unroll
    for (int mf = 0; mf < 4; ++mf) {
#pragma unroll
        for (int nf = 0; nf < 4; ++nf) {
            const int col = ncol0 + wn * 64 + nf * 16 + fr;
            const int rw0 = mrow0 + wm * 64 + mf * 16 + fj * 4;
            const float bc = bias[col];
#pragma unroll
            for (int jj = 0; jj < 4; ++jj) {
                float vv = acc[mf][nf][jj] + bc;
                const size_t idx = (size_t)(rw0 + jj) * DM + col;
                if (mode == 0) {
                    ((__bf16*)g.out[z])[idx] = (__bf16)vv;
                } else if (mode == 3) {
                    ((_Float16*)g.out[z])[idx] = (_Float16)vv;
                } else {
                    if (mode == 2) vv += g.resid[idx];
                    ((float*)g.out[z])[idx] = vv;
                }
            }
        }
    }
}

// ------------------------------------- amplitudes / phases, 16 lanes/head
__global__ __launch_bounds__(256) void amp_fast(
    const float* __restrict__ hs,
    const float* __restrict__ amp_w, const float* __restrict__ amp_b,
    const float* __restrict__ ph_w,  const float* __restrict__ ph_b,
    float* __restrict__ cA, float* __restrict__ sA)
{
    const int s = blockIdx.x;
    __shared__ float hrow[DM];
    for (int i = threadIdx.x; i < DM; i += 256)
        hrow[i] = hs[(size_t)s * DM + i];
    __syncthreads();
    const int h = threadIdx.x >> 4, sub = threadIdx.x & 15;
    const float* aw = amp_w + (size_t)h * DM;
    const float* pw = ph_w  + (size_t)h * DM;
    float da = 0.f, dp = 0.f;
    for (int k = sub; k < DM; k += 16) {
        const float hv = hrow[k];
        da += hv * aw[k];
        dp += hv * pw[k];
    }
#pragma unroll
    for (int off = 8; off >= 1; off >>= 1) {
        da += __shfl_xor(da, off);
        dp += __shfl_xor(dp, off);
    }
    if (sub == 0) {
        da += amp_b[h]; dp += ph_b[h];
        float amp = 1.f / (1.f + expf(-da));
        float ph  = tanhf(dp) * 3.14159265358979323846f;
        cA[s * NH + h] = 0.3f * amp * cosf(ph);
        sA[s * NH + h] = 0.3f * amp * sinf(ph);
    }
}

// ------------------------------------- mixer (v f16) -> mixedT[h*64+o][s] f16
__global__ __launch_bounds__(64) void mixer_naive(
    const _Float16* __restrict__ v, const float* __restrict__ mix_w,
    const float* __restrict__ mix_b,
    const float* __restrict__ cA, const float* __restrict__ sA,
    _Float16* __restrict__ mixedT)
{
    const int s = blockIdx.x, h = blockIdx.y, o = threadIdx.x;
    __shared__ float vrow[HDIM], sup[HDIM];
    vrow[o] = (float)v[(size_t)s * DM + h * HDIM + o];
    __syncthreads();
    float acc = mix_b[h * HDIM + o];
    const float* wr = mix_w + (size_t)h * HDIM * HDIM + o * HDIM;
    for (int d = 0; d < HDIM; ++d) acc += vrow[d] * wr[d];
    sup[o] = acc;
    __syncthreads();
    const float ca = cA[s * NH + h], sa = sA[s * NH + h];
    const float mval = vrow[o] + ca * sup[o] + sa * sup[(o + 63) & 63];
    mixedT[(size_t)(h * HDIM + o) * SEQ + s] = (_Float16)mval;
}

// ---------------------------------------------------- flash MFMA attention
// Block: 128 q-rows x 1 head, 4 waves x 32 q-rows. KV tiles of 64 keys.
// K/EK tiles [key][64d] f16 swizzled; mixedT tile [d][64key] f16 swizzled.
// Online softmax in C-frag layout; P round-trips per-wave LDS (pad 18).
__global__ __launch_bounds__(256) void attn_mfma(
    const _Float16* __restrict__ q, const _Float16* __restrict__ k,
    const _Float16* __restrict__ eq, const _Float16* __restrict__ ek,
    const _Float16* __restrict__ mixedT, __bf16* __restrict__ ctx)
{
    const int h = blockIdx.y;
    const int q0 = blockIdx.x * 128;
    const int tid = threadIdx.x, lane = tid & 63, wv = tid >> 6;
    const int lo = lane & 15, hi = lane >> 4;
    const int hoff = h * HDIM;

    __shared__ _Float16 Kt[64 * 64];
    __shared__ _Float16 Et[64 * 64];
    __shared__ _Float16 Mt[64 * 64];
    __shared__ _Float16 Pt[4 * 2 * 64 * 18];   // per-wave, per-m: [64key][16row+2pad]

    // Q/EQ fragments in regs: 2 m-frags x 2 k-chunks, 8 f16 each
    half8 qa[2][2], ea[2][2];
#pragma unroll
    for (int m = 0; m < 2; ++m) {
        const int row = q0 + wv * 32 + m * 16 + lo;
#pragma unroll
        for (int kk = 0; kk < 2; ++kk) {
            qa[m][kk] = *(const half8*)(q  + (size_t)row * DM + hoff + kk * 32 + hi * 8);
            ea[m][kk] = *(const half8*)(eq + (size_t)row * DM + hoff + kk * 32 + hi * 8);
        }
    }

    f32x4 oacc[2][4];
    float mr[2][4], lr[2][4];
#pragma unroll
    for (int m = 0; m < 2; ++m)
#pragma unroll
        for (int j = 0; j < 4; ++j) {
            mr[m][j] = -3.0e38f; lr[m][j] = 0.f;
#pragma unroll
            for (int e = 0; e < 4; ++e) { /* placeholder */ }
        }
#pragma unroll
    for (int m = 0; m < 2; ++m)
#pragma unroll
        for (int n = 0; n < 4; ++n)
#pragma unroll
            for (int e = 0; e < 4; ++e) oacc[m][n][e] = 0.f;

    // staging: thread owns rows (tid>>3, tid>>3+32), 16B chunk tid&7
    const int srow = tid >> 3, schk = tid & 7;
    const int sdst0 = srow * 64 + ((schk ^ (srow & 7)) << 3);
    const int sdst1 = (srow + 32) * 64 + ((schk ^ (srow & 7)) << 3);

    half8 rk0 = *(const half8*)(k  + (size_t)(srow) * DM + hoff + schk * 8);
    half8 rk1 = *(const half8*)(k  + (size_t)(srow + 32) * DM + hoff + schk * 8);
    half8 re0 = *(const half8*)(ek + (size_t)(srow) * DM + hoff + schk * 8);
    half8 re1 = *(const half8*)(ek + (size_t)(srow + 32) * DM + hoff + schk * 8);
    half8 rm0 = *(const half8*)(mixedT + (size_t)(hoff + srow) * SEQ + schk * 8);
    half8 rm1 = *(const half8*)(mixedT + (size_t)(hoff + srow + 32) * SEQ + schk * 8);

    for (int kt = 0; kt < SEQ; kt += 64) {
        __syncthreads();
        *(half8*)&Kt[sdst0] = rk0; *(half8*)&Kt[sdst1] = rk1;
        *(half8*)&Et[sdst0] = re0; *(half8*)&Et[sdst1] = re1;
        *(half8*)&Mt[sdst0] = rm0; *(half8*)&Mt[sdst1] = rm1;
        __syncthreads();
        if (kt + 64 < SEQ) {
            const int nt = kt + 64;
            rk0 = *(const half8*)(k  + (size_t)(nt + srow) * DM + hoff + schk * 8);
            rk1 = *(const half8*)(k  + (size_t)(nt + srow + 32) * DM + hoff + schk * 8);
            re0 = *(const half8*)(ek + (size_t)(nt + srow) * DM + hoff + schk * 8);
            re1 = *(const half8*)(ek + (size_t)(nt + srow + 32) * DM + hoff + schk * 8);
            rm0 = *(const half8*)(mixedT + (size_t)(hoff + srow) * SEQ + nt + schk * 8);
            rm1 = *(const half8*)(mixedT + (size_t)(hoff + srow + 32) * SEQ + nt + schk * 8);
        }

        // ---- QK^T and EQ*EK^T
        f32x4 sa[2][4], se[2][4];
#pragma unroll
        for (int m = 0; m < 2; ++m)
#pragma unroll
            for (int n = 0; n < 4; ++n)
#pragma unroll
                for (int e = 0; e < 4; ++e) { sa[m][n][e] = 0.f; se[m][n][e] = 0.f; }
#pragma unroll
        for (int kk = 0; kk < 2; ++kk)
#pragma unroll
            for (int nf = 0; nf < 4; ++nf) {
                const int rrow = lo + 16 * nf;
                const int coff = rrow * 64 + (((hi + 4 * kk) ^ (rrow & 7)) << 3);
                half8 kb = *(const half8*)&Kt[coff];
                half8 eb = *(const half8*)&Et[coff];
                sa[0][nf] = __builtin_amdgcn_mfma_f32_16x16x32_f16(qa[0][kk], kb, sa[0][nf], 0, 0, 0);
                sa[1][nf] = __builtin_amdgcn_mfma_f32_16x16x32_f16(qa[1][kk], kb, sa[1][nf], 0, 0, 0);
                se[0][nf] = __builtin_amdgcn_mfma_f32_16x16x32_f16(ea[0][kk], eb, se[0][nf], 0, 0, 0);
                se[1][nf] = __builtin_amdgcn_mfma_f32_16x16x32_f16(ea[1][kk], eb, se[1][nf], 0, 0, 0);
            }

        // ---- logits + online softmax + P->LDS
#pragma unroll
        for (int m = 0; m < 2; ++m) {
            const int qrow = q0 + wv * 32 + m * 16 + hi * 4;
#pragma unroll
            for (int j = 0; j < 4; ++j) {
                float lg[4];
#pragma unroll
                for (int nf = 0; nf < 4; ++nf) {
                    const int key = kt + lo + 16 * nf;
                    int dd = qrow + j - key; dd = dd < 0 ? -dd : dd;
                    const float dec = exp2f(-0.14426950408889634f * (float)dd);
                    lg[nf] = 0.125f * sa[m][nf][j] + 0.0625f * se[m][nf][j] * dec;
                }
                float tm = fmaxf(fmaxf(lg[0], lg[1]), fmaxf(lg[2], lg[3]));
#pragma unroll
                for (int off = 8; off >= 1; off >>= 1) tm = fmaxf(tm, __shfl_xor(tm, off));
                const float mnew = fmaxf(mr[m][j], tm);
                const float corr = expf(mr[m][j] - mnew);
                float ps = 0.f;
#pragma unroll
                for (int nf = 0; nf < 4; ++nf) {
                    const float p = expf(lg[nf] - mnew);
                    sa[m][nf][j] = p;
                    ps += p;
                }
#pragma unroll
                for (int off = 8; off >= 1; off >>= 1) ps += __shfl_xor(ps, off);
                lr[m][j] = lr[m][j] * corr + ps;
                mr[m][j] = mnew;
#pragma unroll
                for (int nfd = 0; nfd < 4; ++nfd) oacc[m][nfd][j] *= corr;
            }
            _Float16* Pw = Pt + (wv * 2 + m) * (64 * 18);
#pragma unroll
            for (int nf = 0; nf < 4; ++nf) {
                half4v pv;
#pragma unroll
                for (int j = 0; j < 4; ++j) pv[j] = (_Float16)sa[m][nf][j];
                *(half4v*)&Pw[(lo + 16 * nf) * 18 + hi * 4] = pv;
            }
        }
        __asm__ volatile("s_waitcnt lgkmcnt(0)" ::: "memory");

        // ---- PV: oacc += P * mixed
#pragma unroll
        for (int kk = 0; kk < 2; ++kk) {
            half8 mb[4];
#pragma unroll
            for (int nfd = 0; nfd < 4; ++nfd) {
                const int rrow = lo + 16 * nfd;
                mb[nfd] = *(const half8*)&Mt[rrow * 64 + (((hi + 4 * kk) ^ (rrow & 7)) << 3)];
            }
#pragma unroll
            for (int m = 0; m < 2; ++m) {
                const _Float16* Pw = Pt + (wv * 2 + m) * (64 * 18);
                half8 pa;
#pragma unroll
                for (int e = 0; e < 8; ++e)
                    pa[e] = Pw[(kk * 32 + hi * 8 + e) * 18 + lo];
#pragma unroll
                for (int nfd = 0; nfd < 4; ++nfd)
                    oacc[m][nfd] = __builtin_amdgcn_mfma_f32_16x16x32_f16(pa, mb[nfd], oacc[m][nfd], 0, 0, 0);
            }
        }
    }

    // ---- epilogue: ctx = oacc / l  (bf16)
#pragma unroll
    for (int m = 0; m < 2; ++m) {
        const int qrow = q0 + wv * 32 + m * 16 + hi * 4;
#pragma unroll
        for (int nfd = 0; nfd < 4; ++nfd) {
            const int d = hoff + lo + 16 * nfd;
#pragma unroll
            for (int j = 0; j < 4; ++j)
                ctx[(size_t)(qrow + j) * DM + d] = (__bf16)(oacc[m][nfd][j] / lr[m][j]);
        }
    }
}

// --------------------------------------------- layer norm, FP32 OUTPUT
__global__ __launch_bounds__(256) void lnorm_f32(
    const float* __restrict__ res, const float* __restrict__ g,
    const float* __restrict__ b, float* __restrict__ out)
{
    const int row = blockIdx.x, tid = threadIdx.x;
    const int wave = tid >> 6, lane = tid & 63;
    __shared__ float red[8];
    const float4 x = reinterpret_cast<const float4*>(res + (size_t)row * DM)[tid];
    float s  = x.x + x.y + x.z + x.w;
    float s2 = x.x * x.x + x.y * x.y + x.z * x.z + x.w * x.w;
#pragma unroll
    for (int off = 32; off >= 1; off >>= 1) {
        s  += __shfl_xor(s, off);
        s2 += __shfl_xor(s2, off);
    }
    if (lane == 0) { red[wave] = s; red[4 + wave] = s2; }
    __syncthreads();
    s  = red[0] + red[1] + red[2] + red[3];
    s2 = red[4] + red[5] + red[6] + red[7];
    const float mu  = s * (1.f / DM);
    const float var = s2 * (1.f / DM) - mu * mu;
    const float inv = rsqrtf(var + 1e-5f);
    const int col = tid * 4;
    float4 o;
    o.x = (x.x - mu) * inv * g[col + 0] + b[col + 0];
    o.y = (x.y - mu) * inv * g[col + 1] + b[col + 1];
    o.z = (x.z - mu) * inv * g[col + 2] + b[col + 2];
    o.w = (x.w - mu) * inv * g[col + 3] + b[col + 3];
    reinterpret_cast<float4*>(out + (size_t)row * DM)[tid] = o;
}

// ---------------------------------------------------------------- launch
// OUTPUT IS FP32. q/k/eq/ek/v/mixedT now f16 (MFMA attention inputs);
// residual + LN stay fp32.  ws layout (~26.3 MB):
//   [0,4M)   hsb bf16            -> overlaid by mixedT (f16) after proj GEMMs
//   [4,10M)  3-slot rotating bf16 weight buffer
//   [10,14M) q f16  [14,18M) k f16      -> overlaid by res fp32 after attn
//   [18,22M) eq f16 [22,26M) ek f16
//   [26M..)  cA/sA
// v (f16) and ctx (bf16) staged in d_out; lnorm rewrites full 8MB fp32 last.
extern "C" void kernel_launch(void* const* d_in, const int* in_sizes, int n_in,
                              void* d_out, int out_size, void* d_ws, size_t ws_size,
                              hipStream_t stream) {
    const float* hs   = (const float*)d_in[0];
    const float* Wq   = (const float*)d_in[1];
    const float* bq   = (const float*)d_in[2];
    const float* Wk   = (const float*)d_in[3];
    const float* bk   = (const float*)d_in[4];
    const float* Wv   = (const float*)d_in[5];
    const float* bv   = (const float*)d_in[6];
    const float* Wo   = (const float*)d_in[7];
    const float* bo   = (const float*)d_in[8];
    const float* Weq  = (const float*)d_in[9];
    const float* beq  = (const float*)d_in[10];
    const float* Wek  = (const float*)d_in[11];
    const float* bek  = (const float*)d_in[12];
    const float* ampw = (const float*)d_in[13];
    const float* ampb = (const float*)d_in[14];
    const float* phw  = (const float*)d_in[15];
    const float* phb  = (const float*)d_in[16];
    const float* mixw = (const float*)d_in[17];
    const float* mixb = (const float*)d_in[18];
    const float* lng  = (const float*)d_in[19];
    const float* lnb  = (const float*)d_in[20];
    float* out = (float*)d_out;

    static const int expect[21] = {
        2097152, 1048576, 1024, 1048576, 1024, 1048576, 1024, 1048576, 1024,
        1048576, 1024, 1048576, 1024, 16384, 16, 16384, 16, 65536, 1024,
        1024, 1024};
    bool ok = (n_in == 21) && (out_size == 2097152);
    if (ok) for (int i = 0; i < 21; ++i) ok = ok && (in_sizes[i] == expect[i]);
    if (!ok) {
        zero_out<<<(out_size + 255) / 256, 256, 0, stream>>>(out, out_size);
        return;
    }

    char* ws = (char*)d_ws;
    __bf16*   hsb = (__bf16*)ws;
    __bf16*   w0  = (__bf16*)(ws + (4  << 20));
    __bf16*   w1  = (__bf16*)(ws + (6  << 20));
    __bf16*   w2  = (__bf16*)(ws + (8  << 20));
    _Float16* qf  = (_Float16*)(ws + (10 << 20));
    _Float16* kf  = (_Float16*)(ws + (14 << 20));
    _Float16* eqf = (_Float16*)(ws + (18 << 20));
    _Float16* ekf = (_Float16*)(ws + (22 << 20));
    float*    cA  = (float*)(ws + (26 << 20));
    float*    sA  = cA + SEQ * NH;
    _Float16* mxT = (_Float16*)hsb;       // overlay: hsb dead after proj GEMMs
    float*    res = (float*)(ws + (10 << 20)); // overlay: q/k dead after attn
    _Float16* vb  = (_Float16*)d_out;
    __bf16*   ctx = (__bf16*)d_out;

    const int H8 = SEQ * DM / 8;
    const int W8 = DM * DM / 8;
    cvt_bf16<<<(H8 + 255) / 256, 256, 0, stream>>>(hs, hsb, H8);
    cvt_bf16<<<(W8 + 255) / 256, 256, 0, stream>>>(Wq, w0, W8);
    cvt_bf16<<<(W8 + 255) / 256, 256, 0, stream>>>(Wk, w1, W8);
    cvt_bf16<<<(W8 + 255) / 256, 256, 0, stream>>>(Wv, w2, W8);

    GemmBatch g1 = {};
    g1.A = hsb;
    g1.W[0] = w0;  g1.W[1] = w1;  g1.W[2] = w2;
    g1.bias[0] = bq; g1.bias[1] = bk; g1.bias[2] = bv;
    g1.out[0] = qf;  g1.out[1] = kf;  g1.out[2] = vb;
    g1.mode[0] = 3;  g1.mode[1] = 3;  g1.mode[2] = 3;
    g1.resid = nullptr;
    gemm_bt<<<dim3(DM / 128, SEQ / 128, 3), 256, 0, stream>>>(g1);

    cvt_bf16<<<(W8 + 255) / 256, 256, 0, stream>>>(Weq, w0, W8);
    cvt_bf16<<<(W8 + 255) / 256, 256, 0, stream>>>(Wek, w1, W8);

    GemmBatch g2 = {};
    g2.A = hsb;
    g2.W[0] = w0;  g2.W[1] = w1;
    g2.bias[0] = beq; g2.bias[1] = bek;
    g2.out[0] = eqf;  g2.out[1] = ekf;
    g2.mode[0] = 3;   g2.mode[1] = 3;
    g2.resid = nullptr;
    gemm_bt<<<dim3(DM / 128, SEQ / 128, 2), 256, 0, stream>>>(g2);

    amp_fast<<<SEQ, 256, 0, stream>>>(hs, ampw, ampb, phw, phb, cA, sA);
    mixer_naive<<<dim3(SEQ, NH), 64, 0, stream>>>(vb, mixw, mixb, cA, sA, mxT);

    attn_mfma<<<dim3(SEQ / 128, NH), 256, 0, stream>>>(qf, kf, eqf, ekf, mxT, ctx);

    cvt_bf16<<<(W8 + 255) / 256, 256, 0, stream>>>(Wo, w0, W8);
    GemmBatch g3 = {};
    g3.A = ctx;
    g3.W[0] = w0; g3.bias[0] = bo; g3.out[0] = res; g3.mode[0] = 2;
    g3.resid = hs;
    gemm_bt<<<dim3(DM / 128, SEQ / 128, 1), 256, 0, stream>>>(g3);

    lnorm_f32<<<SEQ, 256, 0, stream>>>(res, lng, lnb, out);
}

// Round 3
// 354.516 us; speedup vs baseline: 28.4282x; 1.3066x over previous
//
#include <hip/hip_runtime.h>

#define SEQ 2048
#define DM  1024
#define NH  16
#define HDIM 64

typedef __bf16   bf16x8 __attribute__((ext_vector_type(8)));
typedef float    f32x4  __attribute__((ext_vector_type(4)));
typedef _Float16 half8  __attribute__((ext_vector_type(8)));
typedef _Float16 half4v __attribute__((ext_vector_type(4)));

// ------------------------------------------------ sentinel: zero the output
__global__ void zero_out(float* __restrict__ out, int n) {
    int i = blockIdx.x * 256 + threadIdx.x;
    if (i < n) out[i] = 0.f;
}

// ------------------------------------------------ fp32 -> bf16 (8 elems/thr)
__global__ __launch_bounds__(256) void cvt_bf16(
    const float* __restrict__ src, __bf16* __restrict__ dst, int n8)
{
    int i = blockIdx.x * 256 + threadIdx.x;
    if (i >= n8) return;
    const float4* s = reinterpret_cast<const float4*>(src) + (size_t)i * 2;
    float4 x = s[0], y = s[1];
    bf16x8 o;
    o[0] = (__bf16)x.x; o[1] = (__bf16)x.y; o[2] = (__bf16)x.z; o[3] = (__bf16)x.w;
    o[4] = (__bf16)y.x; o[5] = (__bf16)y.y; o[6] = (__bf16)y.z; o[7] = (__bf16)y.w;
    reinterpret_cast<bf16x8*>(dst)[i] = o;
}

// ---------------------------------------- batched weight cvt (6 x 1024x1024)
struct CvtBatch { const float* src[6]; __bf16* dst[6]; };
__global__ __launch_bounds__(256) void cvt_w6(CvtBatch cb) {
    const int z = blockIdx.y;
    int i = blockIdx.x * 256 + threadIdx.x;           // 512*256 = 131072 chunks
    const float4* s = reinterpret_cast<const float4*>(cb.src[z]) + (size_t)i * 2;
    float4 x = s[0], y = s[1];
    bf16x8 o;
    o[0] = (__bf16)x.x; o[1] = (__bf16)x.y; o[2] = (__bf16)x.z; o[3] = (__bf16)x.w;
    o[4] = (__bf16)y.x; o[5] = (__bf16)y.y; o[6] = (__bf16)y.z; o[7] = (__bf16)y.w;
    reinterpret_cast<bf16x8*>(cb.dst[z])[i] = o;
}

// ---------------------------------------- Wsup = blockdiag(mixW) @ Wv (bf16)
// Wsup[h*64+o][c] = sum_d mixw[h,o,d] * Wv[h*64+d][c]
// bsup[h*64+o]    = mixb[h,o] + sum_d mixw[h,o,d] * bv[h*64+d]
__global__ __launch_bounds__(256) void wsup_k(
    const float* __restrict__ mixw, const float* __restrict__ Wv,
    const float* __restrict__ bv, const float* __restrict__ mixb,
    __bf16* __restrict__ w6, float* __restrict__ bsup)
{
    const int ho = blockIdx.x, h = ho >> 6, tid = threadIdx.x;
    __shared__ float mrow[64];
    if (tid < 64) mrow[tid] = mixw[(size_t)ho * 64 + tid];
    __syncthreads();
    const int c0 = tid * 4;
    float a0 = 0.f, a1 = 0.f, a2 = 0.f, a3 = 0.f;
    for (int dd = 0; dd < 64; ++dd) {
        const float4 wv4 = *reinterpret_cast<const float4*>(
            Wv + (size_t)(h * 64 + dd) * DM + c0);
        const float w = mrow[dd];
        a0 += w * wv4.x; a1 += w * wv4.y; a2 += w * wv4.z; a3 += w * wv4.w;
    }
    __bf16* dst = w6 + (size_t)ho * DM + c0;
    dst[0] = (__bf16)a0; dst[1] = (__bf16)a1; dst[2] = (__bf16)a2; dst[3] = (__bf16)a3;
    if (tid == 0) {
        float b = mixb[ho];
        for (int dd = 0; dd < 64; ++dd) b += mrow[dd] * bv[h * 64 + dd];
        bsup[ho] = b;
    }
}

// ---------------------------------------------------------------- MFMA GEMM
// C[m][n] = sum_k A[m][k] * W[n][k] + bias[n]   (B^T layout: both K-contig)
// mode 2: f32 + resid add; mode 3: f16 store.
struct GemmBatch {
    const __bf16* A;
    const __bf16* W[6];
    const float*  bias[6];
    void*         out[6];
    int           mode[6];
    const float*  resid;
};

__device__ __forceinline__ int swz4(int r) { return (r ^ (r >> 2)) & 3; }

__global__ __launch_bounds__(256) void gemm_bt(GemmBatch g) {
    const int z = blockIdx.z;
    const __bf16* __restrict__ A = g.A;
    const __bf16* __restrict__ W = g.W[z];
    const int ncol0 = blockIdx.x * 128;
    const int mrow0 = blockIdx.y * 128;
    const int tid = threadIdx.x, lane = tid & 63, wv = tid >> 6;
    const int wm = wv >> 1, wn = wv & 1;
    const int fr = lane & 15, fj = lane >> 4;

    __shared__ __bf16 As[128 * 32];
    __shared__ __bf16 Bs[128 * 32];

    f32x4 acc[4][4];
#pragma unroll
    for (int i = 0; i < 4; ++i)
#pragma unroll
        for (int j = 0; j < 4; ++j)
#pragma unroll
            for (int e = 0; e < 4; ++e) acc[i][j][e] = 0.f;

    const int c0 = tid, c1 = tid + 256;
    const int r0 = c0 >> 2, j0 = c0 & 3;
    const int r1 = c1 >> 2, j1 = c1 & 3;
    const int la0 = r0 * 32 + ((j0 ^ swz4(r0)) << 3);
    const int la1 = r1 * 32 + ((j1 ^ swz4(r1)) << 3);

    const __bf16* Ap0 = A + (size_t)(mrow0 + r0) * DM + j0 * 8;
    const __bf16* Ap1 = A + (size_t)(mrow0 + r1) * DM + j1 * 8;
    const __bf16* Wp0 = W + (size_t)(ncol0 + r0) * DM + j0 * 8;
    const __bf16* Wp1 = W + (size_t)(ncol0 + r1) * DM + j1 * 8;

    bf16x8 ra0 = *(const bf16x8*)(Ap0);
    bf16x8 ra1 = *(const bf16x8*)(Ap1);
    bf16x8 rb0 = *(const bf16x8*)(Wp0);
    bf16x8 rb1 = *(const bf16x8*)(Wp1);

    for (int kt = 0; kt < DM; kt += 32) {
        __syncthreads();
        *(bf16x8*)(As + la0) = ra0;
        *(bf16x8*)(As + la1) = ra1;
        *(bf16x8*)(Bs + la0) = rb0;
        *(bf16x8*)(Bs + la1) = rb1;
        __syncthreads();
        if (kt + 32 < DM) {
            ra0 = *(const bf16x8*)(Ap0 + kt + 32);
            ra1 = *(const bf16x8*)(Ap1 + kt + 32);
            rb0 = *(const bf16x8*)(Wp0 + kt + 32);
            rb1 = *(const bf16x8*)(Wp1 + kt + 32);
        }
        bf16x8 af[4], bfv[4];
#pragma unroll
        for (int mf = 0; mf < 4; ++mf) {
            int r = wm * 64 + mf * 16 + fr;
            af[mf] = *(const bf16x8*)(As + r * 32 + ((fj ^ swz4(r)) << 3));
        }
#pragma unroll
        for (int nf = 0; nf < 4; ++nf) {
            int r = wn * 64 + nf * 16 + fr;
            bfv[nf] = *(const bf16x8*)(Bs + r * 32 + ((fj ^ swz4(r)) << 3));
        }
#pragma unroll
        for (int mf = 0; mf < 4; ++mf)
#pragma unroll
            for (int nf = 0; nf < 4; ++nf)
                acc[mf][nf] = __builtin_amdgcn_mfma_f32_16x16x32_bf16(
                    af[mf], bfv[nf], acc[mf][nf], 0, 0, 0);
    }

    const int mode = g.mode[z];
    const float* __restrict__ bias = g.bias[z];
#pragma unroll
    for (int mf = 0; mf < 4; ++mf) {
#pragma unroll
        for (int nf = 0; nf < 4; ++nf) {
            const int col = ncol0 + wn * 64 + nf * 16 + fr;
            const int rw0 = mrow0 + wm * 64 + mf * 16 + fj * 4;
            const float bc = bias[col];
#pragma unroll
            for (int jj = 0; jj < 4; ++jj) {
                float vv = acc[mf][nf][jj] + bc;
                const size_t idx = (size_t)(rw0 + jj) * DM + col;
                if (mode == 3) {
                    ((_Float16*)g.out[z])[idx] = (_Float16)vv;
                } else {
                    if (mode == 2) vv += g.resid[idx];
                    ((float*)g.out[z])[idx] = vv;
                }
            }
        }
    }
}

// ------------------------------------- amplitudes / phases, 16 lanes/head
__global__ __launch_bounds__(256) void amp_fast(
    const float* __restrict__ hs,
    const float* __restrict__ amp_w, const float* __restrict__ amp_b,
    const float* __restrict__ ph_w,  const float* __restrict__ ph_b,
    float* __restrict__ cA, float* __restrict__ sA)
{
    const int s = blockIdx.x;
    __shared__ float hrow[DM];
    for (int i = threadIdx.x; i < DM; i += 256)
        hrow[i] = hs[(size_t)s * DM + i];
    __syncthreads();
    const int h = threadIdx.x >> 4, sub = threadIdx.x & 15;
    const float* aw = amp_w + (size_t)h * DM;
    const float* pw = ph_w  + (size_t)h * DM;
    float da = 0.f, dp = 0.f;
    for (int k = sub; k < DM; k += 16) {
        const float hv = hrow[k];
        da += hv * aw[k];
        dp += hv * pw[k];
    }
#pragma unroll
    for (int off = 8; off >= 1; off >>= 1) {
        da += __shfl_xor(da, off);
        dp += __shfl_xor(dp, off);
    }
    if (sub == 0) {
        da += amp_b[h]; dp += ph_b[h];
        float amp = 1.f / (1.f + expf(-da));
        float ph  = tanhf(dp) * 3.14159265358979323846f;
        cA[s * NH + h] = 0.3f * amp * cosf(ph);
        sA[s * NH + h] = 0.3f * amp * sinf(ph);
    }
}

// ----------------- mixedT[h*64+o][s] = v + cA*sup + sA*roll(sup)  (f16)
// gathers are L1-resident (per-block working set 64s x 64o x 2 arrays = 16KB)
__global__ __launch_bounds__(256) void mixT_fuse(
    const _Float16* __restrict__ vb, const _Float16* __restrict__ supf,
    const float* __restrict__ cA, const float* __restrict__ sA,
    _Float16* __restrict__ mixedT)
{
    const int h = blockIdx.x, st = blockIdx.y;        // 16 x 64
    const int o = threadIdx.x >> 2, sc = threadIdx.x & 3;
    const int s0 = st * 32 + sc * 8;
    const int ho = h * 64 + o, op = h * 64 + ((o + 63) & 63);
    half8 m;
#pragma unroll
    for (int e = 0; e < 8; ++e) {
        const int s = s0 + e;
        const float v  = (float)vb[(size_t)s * DM + ho];
        const float su = (float)supf[(size_t)s * DM + ho];
        const float s2 = (float)supf[(size_t)s * DM + op];
        m[e] = (_Float16)(v + cA[s * NH + h] * su + sA[s * NH + h] * s2);
    }
    *reinterpret_cast<half8*>(mixedT + (size_t)ho * SEQ + s0) = m;
}

// ---------------------------------------------------- flash MFMA attention
// Block: 64 q-rows x 1 head, 4 waves x 16 q-rows. KV tiles of 64 keys.
// Defer-max online softmax (m0=0, THR=8): no in-loop cross-lane reductions;
// guarded rescale path for arbitrary data. Grid 512 blocks = 2/CU.
__global__ __launch_bounds__(256) void attn_mfma(
    const _Float16* __restrict__ q, const _Float16* __restrict__ k,
    const _Float16* __restrict__ eq, const _Float16* __restrict__ ek,
    const _Float16* __restrict__ mixedT, __bf16* __restrict__ ctx)
{
    const int h = blockIdx.y;
    const int q0 = blockIdx.x * 64;
    const int tid = threadIdx.x, lane = tid & 63, wv = tid >> 6;
    const int lo = lane & 15, hi = lane >> 4;
    const int hoff = h * HDIM;

    __shared__ _Float16 Kt[64 * 64];
    __shared__ _Float16 Et[64 * 64];
    __shared__ _Float16 Mt[64 * 64];
    __shared__ _Float16 Pt[4][64 * 18];    // per-wave [64key][16row+2pad]

    // Q/EQ fragments: row = q0 + wv*16 + lo, k-chunk kk*32 + hi*8
    half8 qa[2], ea[2];
#pragma unroll
    for (int kk = 0; kk < 2; ++kk) {
        const int row = q0 + wv * 16 + lo;
        qa[kk] = *(const half8*)(q  + (size_t)row * DM + hoff + kk * 32 + hi * 8);
        ea[kk] = *(const half8*)(eq + (size_t)row * DM + hoff + kk * 32 + hi * 8);
    }

    f32x4 oacc[4];
    float mr[4], lr[4];
#pragma unroll
    for (int j = 0; j < 4; ++j) { mr[j] = 0.f; lr[j] = 0.f; }
#pragma unroll
    for (int n = 0; n < 4; ++n)
#pragma unroll
        for (int e = 0; e < 4; ++e) oacc[n][e] = 0.f;

    const int srow = tid >> 3, schk = tid & 7;
    const int sdst0 = srow * 64 + ((schk ^ (srow & 7)) << 3);
    const int sdst1 = (srow + 32) * 64 + ((schk ^ (srow & 7)) << 3);

    half8 rk0 = *(const half8*)(k  + (size_t)(srow) * DM + hoff + schk * 8);
    half8 rk1 = *(const half8*)(k  + (size_t)(srow + 32) * DM + hoff + schk * 8);
    half8 re0 = *(const half8*)(ek + (size_t)(srow) * DM + hoff + schk * 8);
    half8 re1 = *(const half8*)(ek + (size_t)(srow + 32) * DM + hoff + schk * 8);
    half8 rm0 = *(const half8*)(mixedT + (size_t)(hoff + srow) * SEQ + schk * 8);
    half8 rm1 = *(const half8*)(mixedT + (size_t)(hoff + srow + 32) * SEQ + schk * 8);

    for (int kt = 0; kt < SEQ; kt += 64) {
        __syncthreads();
        *(half8*)&Kt[sdst0] = rk0; *(half8*)&Kt[sdst1] = rk1;
        *(half8*)&Et[sdst0] = re0; *(half8*)&Et[sdst1] = re1;
        *(half8*)&Mt[sdst0] = rm0; *(half8*)&Mt[sdst1] = rm1;
        __syncthreads();
        if (kt + 64 < SEQ) {
            const int nt = kt + 64;
            rk0 = *(const half8*)(k  + (size_t)(nt + srow) * DM + hoff + schk * 8);
            rk1 = *(const half8*)(k  + (size_t)(nt + srow + 32) * DM + hoff + schk * 8);
            re0 = *(const half8*)(ek + (size_t)(nt + srow) * DM + hoff + schk * 8);
            re1 = *(const half8*)(ek + (size_t)(nt + srow + 32) * DM + hoff + schk * 8);
            rm0 = *(const half8*)(mixedT + (size_t)(hoff + srow) * SEQ + nt + schk * 8);
            rm1 = *(const half8*)(mixedT + (size_t)(hoff + srow + 32) * SEQ + nt + schk * 8);
        }

        // ---- QK^T and EQ*EK^T
        f32x4 sa[4], se[4];
#pragma unroll
        for (int n = 0; n < 4; ++n)
#pragma unroll
            for (int e = 0; e < 4; ++e) { sa[n][e] = 0.f; se[n][e] = 0.f; }
#pragma unroll
        for (int kk = 0; kk < 2; ++kk)
#pragma unroll
            for (int nf = 0; nf < 4; ++nf) {
                const int rrow = lo + 16 * nf;
                const int coff = rrow * 64 + (((hi + 4 * kk) ^ (rrow & 7)) << 3);
                half8 kb = *(const half8*)&Kt[coff];
                half8 eb = *(const half8*)&Et[coff];
                sa[nf] = __builtin_amdgcn_mfma_f32_16x16x32_f16(qa[kk], kb, sa[nf], 0, 0, 0);
                se[nf] = __builtin_amdgcn_mfma_f32_16x16x32_f16(ea[kk], eb, se[nf], 0, 0, 0);
            }

        // ---- logits (decay inline) + defer-max check
        float lg[4][4];
        bool exc = false;
        const int qrow = q0 + wv * 16 + hi * 4;
#pragma unroll
        for (int nf = 0; nf < 4; ++nf) {
            const int key = kt + nf * 16 + lo;
#pragma unroll
            for (int j = 0; j < 4; ++j) {
                int dd = qrow + j - key; dd = dd < 0 ? -dd : dd;
                const float dec = exp2f(-0.14426950408889634f * (float)dd);
                const float v = 0.125f * sa[nf][j] + 0.0625f * se[nf][j] * dec;
                lg[nf][j] = v;
                exc |= (v > mr[j] + 8.f);
            }
        }
        if (__any((int)exc)) {                       // rare rescale path
#pragma unroll
            for (int j = 0; j < 4; ++j) {
                float tm = fmaxf(fmaxf(lg[0][j], lg[1][j]), fmaxf(lg[2][j], lg[3][j]));
#pragma unroll
                for (int off = 8; off >= 1; off >>= 1) tm = fmaxf(tm, __shfl_xor(tm, off));
                const float mnew = fmaxf(mr[j], tm);
                const float corr = expf(mr[j] - mnew);
                lr[j] *= corr; mr[j] = mnew;
#pragma unroll
                for (int nfd = 0; nfd < 4; ++nfd) oacc[nfd][j] *= corr;
            }
        }
        // ---- P = exp(lg - m), lane-local l accumulation, P -> LDS (f16)
        _Float16* Pw = Pt[wv];
#pragma unroll
        for (int nf = 0; nf < 4; ++nf) {
            half4v pv;
#pragma unroll
            for (int j = 0; j < 4; ++j) {
                const float p = expf(lg[nf][j] - mr[j]);
                lr[j] += p;
                pv[j] = (_Float16)p;
            }
            *(half4v*)&Pw[(lo + 16 * nf) * 18 + hi * 4] = pv;
        }
        __asm__ volatile("s_waitcnt lgkmcnt(0)" ::: "memory");

        // ---- PV: oacc += P * mixed
#pragma unroll
        for (int kk = 0; kk < 2; ++kk) {
            half8 mb[4];
#pragma unroll
            for (int nfd = 0; nfd < 4; ++nfd) {
                const int rrow = lo + 16 * nfd;
                mb[nfd] = *(const half8*)&Mt[rrow * 64 + (((hi + 4 * kk) ^ (rrow & 7)) << 3)];
            }
            half8 pa;
#pragma unroll
            for (int e = 0; e < 8; ++e)
                pa[e] = Pw[(kk * 32 + hi * 8 + e) * 18 + lo];
#pragma unroll
            for (int nfd = 0; nfd < 4; ++nfd)
                oacc[nfd] = __builtin_amdgcn_mfma_f32_16x16x32_f16(pa, mb[nfd], oacc[nfd], 0, 0, 0);
        }
    }

    // ---- epilogue: reduce l over the 16-lane row group, normalize, store
#pragma unroll
    for (int j = 0; j < 4; ++j) {
#pragma unroll
        for (int off = 8; off >= 1; off >>= 1) lr[j] += __shfl_xor(lr[j], off);
    }
    const int qrow = q0 + wv * 16 + hi * 4;
#pragma unroll
    for (int nfd = 0; nfd < 4; ++nfd) {
        const int d = hoff + lo + 16 * nfd;
#pragma unroll
        for (int j = 0; j < 4; ++j)
            ctx[(size_t)(qrow + j) * DM + d] = (__bf16)(oacc[nfd][j] / lr[j]);
    }
}

// --------------------------------------------- layer norm, FP32 OUTPUT
__global__ __launch_bounds__(256) void lnorm_f32(
    const float* __restrict__ res, const float* __restrict__ g,
    const float* __restrict__ b, float* __restrict__ out)
{
    const int row = blockIdx.x, tid = threadIdx.x;
    const int wave = tid >> 6, lane = tid & 63;
    __shared__ float red[8];
    const float4 x = reinterpret_cast<const float4*>(res + (size_t)row * DM)[tid];
    float s  = x.x + x.y + x.z + x.w;
    float s2 = x.x * x.x + x.y * x.y + x.z * x.z + x.w * x.w;
#pragma unroll
    for (int off = 32; off >= 1; off >>= 1) {
        s  += __shfl_xor(s, off);
        s2 += __shfl_xor(s2, off);
    }
    if (lane == 0) { red[wave] = s; red[4 + wave] = s2; }
    __syncthreads();
    s  = red[0] + red[1] + red[2] + red[3];
    s2 = red[4] + red[5] + red[6] + red[7];
    const float mu  = s * (1.f / DM);
    const float var = s2 * (1.f / DM) - mu * mu;
    const float inv = rsqrtf(var + 1e-5f);
    const int col = tid * 4;
    float4 o;
    o.x = (x.x - mu) * inv * g[col + 0] + b[col + 0];
    o.y = (x.y - mu) * inv * g[col + 1] + b[col + 1];
    o.z = (x.z - mu) * inv * g[col + 2] + b[col + 2];
    o.w = (x.w - mu) * inv * g[col + 3] + b[col + 3];
    reinterpret_cast<float4*>(out + (size_t)row * DM)[tid] = o;
}

// ---------------------------------------------------------------- launch
// OUTPUT IS FP32. ws layout (~34.3 MB, under proven 36.3 MB budget):
//   [0,4M)    hsb bf16        -> overlaid by mixedT f16 (hsb dead after g1)
//   [4,16M)   w0..w5 bf16 (Wq,Wk,Wv,Weq,Wek,Wo), 2MB each
//   [16,18M)  w6 = Wsup bf16
//   [18,22M)  qf f16   [22,26M) kf f16   } res f32 overlays [18,26M) post-attn
//   [26,30M)  eqf f16  [30,34M) ekf f16
//   [34M..)   cA (128K), sA (128K), bsup (4K)
// d_out staging: vb f16 [0,4M), supf f16 [4,8M); both dead after mixT_fuse;
// ctx bf16 then occupies [0,4M); lnorm rewrites the full 8MB fp32 at the end.
extern "C" void kernel_launch(void* const* d_in, const int* in_sizes, int n_in,
                              void* d_out, int out_size, void* d_ws, size_t ws_size,
                              hipStream_t stream) {
    const float* hs   = (const float*)d_in[0];
    const float* Wq   = (const float*)d_in[1];
    const float* bq   = (const float*)d_in[2];
    const float* Wk   = (const float*)d_in[3];
    const float* bk   = (const float*)d_in[4];
    const float* Wv   = (const float*)d_in[5];
    const float* bv   = (const float*)d_in[6];
    const float* Wo   = (const float*)d_in[7];
    const float* bo   = (const float*)d_in[8];
    const float* Weq  = (const float*)d_in[9];
    const float* beq  = (const float*)d_in[10];
    const float* Wek  = (const float*)d_in[11];
    const float* bek  = (const float*)d_in[12];
    const float* ampw = (const float*)d_in[13];
    const float* ampb = (const float*)d_in[14];
    const float* phw  = (const float*)d_in[15];
    const float* phb  = (const float*)d_in[16];
    const float* mixw = (const float*)d_in[17];
    const float* mixb = (const float*)d_in[18];
    const float* lng  = (const float*)d_in[19];
    const float* lnb  = (const float*)d_in[20];
    float* out = (float*)d_out;

    static const int expect[21] = {
        2097152, 1048576, 1024, 1048576, 1024, 1048576, 1024, 1048576, 1024,
        1048576, 1024, 1048576, 1024, 16384, 16, 16384, 16, 65536, 1024,
        1024, 1024};
    bool ok = (n_in == 21) && (out_size == 2097152);
    if (ok) for (int i = 0; i < 21; ++i) ok = ok && (in_sizes[i] == expect[i]);
    if (!ok) {
        zero_out<<<(out_size + 255) / 256, 256, 0, stream>>>(out, out_size);
        return;
    }

    char* ws = (char*)d_ws;
    __bf16*   hsb = (__bf16*)ws;
    __bf16*   w0  = (__bf16*)(ws + (4  << 20));
    __bf16*   w1  = (__bf16*)(ws + (6  << 20));
    __bf16*   w2  = (__bf16*)(ws + (8  << 20));
    __bf16*   w3  = (__bf16*)(ws + (10 << 20));
    __bf16*   w4  = (__bf16*)(ws + (12 << 20));
    __bf16*   w5  = (__bf16*)(ws + (14 << 20));
    __bf16*   w6  = (__bf16*)(ws + (16 << 20));
    _Float16* qf  = (_Float16*)(ws + (18 << 20));
    _Float16* kf  = (_Float16*)(ws + (22 << 20));
    _Float16* eqf = (_Float16*)(ws + (26 << 20));
    _Float16* ekf = (_Float16*)(ws + (30 << 20));
    float*    cA  = (float*)(ws + (34 << 20));
    float*    sA  = cA + SEQ * NH;
    float*    bsup = sA + SEQ * NH;
    _Float16* mxT = (_Float16*)hsb;            // overlay: hsb dead after g1
    float*    res = (float*)(ws + (18 << 20)); // overlay: q/k dead after attn
    _Float16* vb   = (_Float16*)d_out;
    _Float16* supf = (_Float16*)((char*)d_out + (4 << 20));
    __bf16*   ctx  = (__bf16*)d_out;

    const int H8 = SEQ * DM / 8;
    cvt_bf16<<<(H8 + 255) / 256, 256, 0, stream>>>(hs, hsb, H8);

    CvtBatch cb;
    cb.src[0] = Wq;  cb.dst[0] = w0;
    cb.src[1] = Wk;  cb.dst[1] = w1;
    cb.src[2] = Wv;  cb.dst[2] = w2;
    cb.src[3] = Weq; cb.dst[3] = w3;
    cb.src[4] = Wek; cb.dst[4] = w4;
    cb.src[5] = Wo;  cb.dst[5] = w5;
    cvt_w6<<<dim3(512, 6), 256, 0, stream>>>(cb);

    wsup_k<<<1024, 256, 0, stream>>>(mixw, Wv, bv, mixb, w6, bsup);
    amp_fast<<<SEQ, 256, 0, stream>>>(hs, ampw, ampb, phw, phb, cA, sA);

    GemmBatch g1 = {};
    g1.A = hsb;
    g1.W[0] = w0; g1.bias[0] = bq;   g1.out[0] = qf;   g1.mode[0] = 3;
    g1.W[1] = w1; g1.bias[1] = bk;   g1.out[1] = kf;   g1.mode[1] = 3;
    g1.W[2] = w2; g1.bias[2] = bv;   g1.out[2] = vb;   g1.mode[2] = 3;
    g1.W[3] = w3; g1.bias[3] = beq;  g1.out[3] = eqf;  g1.mode[3] = 3;
    g1.W[4] = w4; g1.bias[4] = bek;  g1.out[4] = ekf;  g1.mode[4] = 3;
    g1.W[5] = w6; g1.bias[5] = bsup; g1.out[5] = supf; g1.mode[5] = 3;
    g1.resid = nullptr;
    gemm_bt<<<dim3(DM / 128, SEQ / 128, 6), 256, 0, stream>>>(g1);

    mixT_fuse<<<dim3(NH, SEQ / 32), 256, 0, stream>>>(vb, supf, cA, sA, mxT);

    attn_mfma<<<dim3(SEQ / 64, NH), 256, 0, stream>>>(qf, kf, eqf, ekf, mxT, ctx);

    GemmBatch g3 = {};
    g3.A = ctx;
    g3.W[0] = w5; g3.bias[0] = bo; g3.out[0] = res; g3.mode[0] = 2;
    g3.resid = hs;
    gemm_bt<<<dim3(DM / 128, SEQ / 128, 1), 256, 0, stream>>>(g3);

    lnorm_f32<<<SEQ, 256, 0, stream>>>(res, lng, lnb, out);
}

// Round 4
// 303.629 us; speedup vs baseline: 33.1927x; 1.1676x over previous
//
#include <hip/hip_runtime.h>

#define SEQ 2048
#define DM  1024
#define NH  16
#define HDIM 64

typedef __bf16   bf16x8 __attribute__((ext_vector_type(8)));
typedef float    f32x4  __attribute__((ext_vector_type(4)));
typedef _Float16 half8  __attribute__((ext_vector_type(8)));
typedef _Float16 half4v __attribute__((ext_vector_type(4)));

// async global->LDS 16B (linear LDS dst = wave-uniform base + lane*16)
__device__ __forceinline__ void gload16(const void* g, void* l) {
    __builtin_amdgcn_global_load_lds(
        (const __attribute__((address_space(1))) unsigned int*)g,
        (__attribute__((address_space(3))) unsigned int*)l, 16, 0, 0);
}

// ------------------------------------------------ sentinel: zero the output
__global__ void zero_out(float* __restrict__ out, int n) {
    int i = blockIdx.x * 256 + threadIdx.x;
    if (i < n) out[i] = 0.f;
}

// ------------------------------------------------ fp32 -> bf16 (8 elems/thr)
__global__ __launch_bounds__(256) void cvt_bf16(
    const float* __restrict__ src, __bf16* __restrict__ dst, int n8)
{
    int i = blockIdx.x * 256 + threadIdx.x;
    if (i >= n8) return;
    const float4* s = reinterpret_cast<const float4*>(src) + (size_t)i * 2;
    float4 x = s[0], y = s[1];
    bf16x8 o;
    o[0] = (__bf16)x.x; o[1] = (__bf16)x.y; o[2] = (__bf16)x.z; o[3] = (__bf16)x.w;
    o[4] = (__bf16)y.x; o[5] = (__bf16)y.y; o[6] = (__bf16)y.z; o[7] = (__bf16)y.w;
    reinterpret_cast<bf16x8*>(dst)[i] = o;
}

// ---------------------------------------- batched weight cvt (6 x 1024x1024)
struct CvtBatch { const float* src[6]; __bf16* dst[6]; };
__global__ __launch_bounds__(256) void cvt_w6(CvtBatch cb) {
    const int z = blockIdx.y;
    int i = blockIdx.x * 256 + threadIdx.x;
    const float4* s = reinterpret_cast<const float4*>(cb.src[z]) + (size_t)i * 2;
    float4 x = s[0], y = s[1];
    bf16x8 o;
    o[0] = (__bf16)x.x; o[1] = (__bf16)x.y; o[2] = (__bf16)x.z; o[3] = (__bf16)x.w;
    o[4] = (__bf16)y.x; o[5] = (__bf16)y.y; o[6] = (__bf16)y.z; o[7] = (__bf16)y.w;
    reinterpret_cast<bf16x8*>(cb.dst[z])[i] = o;
}

// ---------------------------------------- Wsup = blockdiag(mixW) @ Wv (bf16)
__global__ __launch_bounds__(256) void wsup_k(
    const float* __restrict__ mixw, const float* __restrict__ Wv,
    const float* __restrict__ bv, const float* __restrict__ mixb,
    __bf16* __restrict__ w6, float* __restrict__ bsup)
{
    const int ho = blockIdx.x, h = ho >> 6, tid = threadIdx.x;
    __shared__ float mrow[64];
    if (tid < 64) mrow[tid] = mixw[(size_t)ho * 64 + tid];
    __syncthreads();
    const int c0 = tid * 4;
    float a0 = 0.f, a1 = 0.f, a2 = 0.f, a3 = 0.f;
    for (int dd = 0; dd < 64; ++dd) {
        const float4 wv4 = *reinterpret_cast<const float4*>(
            Wv + (size_t)(h * 64 + dd) * DM + c0);
        const float w = mrow[dd];
        a0 += w * wv4.x; a1 += w * wv4.y; a2 += w * wv4.z; a3 += w * wv4.w;
    }
    __bf16* dst = w6 + (size_t)ho * DM + c0;
    dst[0] = (__bf16)a0; dst[1] = (__bf16)a1; dst[2] = (__bf16)a2; dst[3] = (__bf16)a3;
    if (tid == 0) {
        float b = mixb[ho];
        for (int dd = 0; dd < 64; ++dd) b += mrow[dd] * bv[h * 64 + dd];
        bsup[ho] = b;
    }
}

// ---------------------------------------------------------------- MFMA GEMM
// C[m][n] = sum_k A[m][k] * W[n][k] + bias[n]   (B^T layout: both K-contig)
// Staging via global_load_lds(16B): linear LDS dst, XOR-swizzle applied to
// the GLOBAL source chunk index (involution; read-side XOR recovers).
// mode 2: f32 + resid add; mode 3: f16 store.
struct GemmBatch {
    const __bf16* A;
    const __bf16* W[6];
    const float*  bias[6];
    void*         out[6];
    int           mode[6];
    const float*  resid;
};

__device__ __forceinline__ int swz4(int r) { return (r ^ (r >> 2)) & 3; }

__global__ __launch_bounds__(256) void gemm_bt(GemmBatch g) {
    const int z = blockIdx.z;
    const __bf16* __restrict__ A = g.A;
    const __bf16* __restrict__ W = g.W[z];
    const int ncol0 = blockIdx.x * 128;
    const int mrow0 = blockIdx.y * 128;
    const int tid = threadIdx.x, lane = tid & 63, wv = tid >> 6;
    const int wm = wv >> 1, wn = wv & 1;
    const int fr = lane & 15, fj = lane >> 4;

    __shared__ __bf16 As[128 * 32];
    __shared__ __bf16 Bs[128 * 32];

    f32x4 acc[4][4];
#pragma unroll
    for (int i = 0; i < 4; ++i)
#pragma unroll
        for (int j = 0; j < 4; ++j)
#pragma unroll
            for (int e = 0; e < 4; ++e) acc[i][j][e] = 0.f;

    // staging geometry: instr i covers rows [i*64 + wv*16, +16), chunk = lane&3
    const int row0 = wv * 16 + (lane >> 2);
    const int row1 = row0 + 64;
    const int jl   = lane & 3;
    const int dstA0 = row0 * 32 + jl * 8;       // bf16 elems (linear, no swz)
    const int dstA1 = row1 * 32 + jl * 8;
    const __bf16* ApS0 = A + (size_t)(mrow0 + row0) * DM + (jl ^ swz4(row0)) * 8;
    const __bf16* ApS1 = A + (size_t)(mrow0 + row1) * DM + (jl ^ swz4(row1)) * 8;
    const __bf16* WpS0 = W + (size_t)(ncol0 + row0) * DM + (jl ^ swz4(row0)) * 8;
    const __bf16* WpS1 = W + (size_t)(ncol0 + row1) * DM + (jl ^ swz4(row1)) * 8;

    for (int kt = 0; kt < DM; kt += 32) {
        __syncthreads();                          // prev-iter LDS reads done
        gload16(ApS0 + kt, As + dstA0);
        gload16(ApS1 + kt, As + dstA1);
        gload16(WpS0 + kt, Bs + dstA0);
        gload16(WpS1 + kt, Bs + dstA1);
        __syncthreads();                          // vmcnt(0) drained by compiler

        bf16x8 af[4], bfv[4];
#pragma unroll
        for (int mf = 0; mf < 4; ++mf) {
            int r = wm * 64 + mf * 16 + fr;
            af[mf] = *(const bf16x8*)(As + r * 32 + ((fj ^ swz4(r)) << 3));
        }
#pragma unroll
        for (int nf = 0; nf < 4; ++nf) {
            int r = wn * 64 + nf * 16 + fr;
            bfv[nf] = *(const bf16x8*)(Bs + r * 32 + ((fj ^ swz4(r)) << 3));
        }
#pragma unroll
        for (int mf = 0; mf < 4; ++mf)
#pragma unroll
            for (int nf = 0; nf < 4; ++nf)
                acc[mf][nf] = __builtin_amdgcn_mfma_f32_16x16x32_bf16(
                    af[mf], bfv[nf], acc[mf][nf], 0, 0, 0);
    }

    const int mode = g.mode[z];
    const float* __restrict__ bias = g.bias[z];
#pragma unroll
    for (int mf = 0; mf < 4; ++mf) {
#pragma unroll
        for (int nf = 0; nf < 4; ++nf) {
            const int col = ncol0 + wn * 64 + nf * 16 + fr;
            const int rw0 = mrow0 + wm * 64 + mf * 16 + fj * 4;
            const float bc = bias[col];
#pragma unroll
            for (int jj = 0; jj < 4; ++jj) {
                float vv = acc[mf][nf][jj] + bc;
                const size_t idx = (size_t)(rw0 + jj) * DM + col;
                if (mode == 3) {
                    ((_Float16*)g.out[z])[idx] = (_Float16)vv;
                } else {
                    if (mode == 2) vv += g.resid[idx];
                    ((float*)g.out[z])[idx] = vv;
                }
            }
        }
    }
}

// ------------------------------------- amplitudes / phases, 16 lanes/head
__global__ __launch_bounds__(256) void amp_fast(
    const float* __restrict__ hs,
    const float* __restrict__ amp_w, const float* __restrict__ amp_b,
    const float* __restrict__ ph_w,  const float* __restrict__ ph_b,
    float* __restrict__ cA, float* __restrict__ sA)
{
    const int s = blockIdx.x;
    __shared__ float hrow[DM];
    for (int i = threadIdx.x; i < DM; i += 256)
        hrow[i] = hs[(size_t)s * DM + i];
    __syncthreads();
    const int h = threadIdx.x >> 4, sub = threadIdx.x & 15;
    const float* aw = amp_w + (size_t)h * DM;
    const float* pw = ph_w  + (size_t)h * DM;
    float da = 0.f, dp = 0.f;
    for (int k = sub; k < DM; k += 16) {
        const float hv = hrow[k];
        da += hv * aw[k];
        dp += hv * pw[k];
    }
#pragma unroll
    for (int off = 8; off >= 1; off >>= 1) {
        da += __shfl_xor(da, off);
        dp += __shfl_xor(dp, off);
    }
    if (sub == 0) {
        da += amp_b[h]; dp += ph_b[h];
        float amp = 1.f / (1.f + expf(-da));
        float ph  = tanhf(dp) * 3.14159265358979323846f;
        cA[s * NH + h] = 0.3f * amp * cosf(ph);
        sA[s * NH + h] = 0.3f * amp * sinf(ph);
    }
}

// ----------------- mixedT[h*64+o][s] = v + cA*sup + sA*roll(sup)  (f16)
__global__ __launch_bounds__(256) void mixT_fuse(
    const _Float16* __restrict__ vb, const _Float16* __restrict__ supf,
    const float* __restrict__ cA, const float* __restrict__ sA,
    _Float16* __restrict__ mixedT)
{
    const int h = blockIdx.x, st = blockIdx.y;        // 16 x 64
    const int o = threadIdx.x >> 2, sc = threadIdx.x & 3;
    const int s0 = st * 32 + sc * 8;
    const int ho = h * 64 + o, op = h * 64 + ((o + 63) & 63);
    half8 m;
#pragma unroll
    for (int e = 0; e < 8; ++e) {
        const int s = s0 + e;
        const float v  = (float)vb[(size_t)s * DM + ho];
        const float su = (float)supf[(size_t)s * DM + ho];
        const float s2 = (float)supf[(size_t)s * DM + op];
        m[e] = (_Float16)(v + cA[s * NH + h] * su + sA[s * NH + h] * s2);
    }
    *reinterpret_cast<half8*>(mixedT + (size_t)ho * SEQ + s0) = m;
}

// ---------------------------------------------------- flash MFMA attention
// Block: 64 q-rows x 1 head, 4 waves x 16 q-rows. KV tiles of 64 keys.
// Defer-max online softmax (m0=0, THR=8). BAND SPARSITY: the entanglement
// term decays as e^(-0.1|dq-dk|) < 1.1e-7 beyond |delta|=160 and |esc|<=
// ~0.002 at dec=1 -> for tiles with min|delta| > 160 skip EK staging, the
// EQ*EK^T MFMAs and the per-logit decay chain entirely (error < 2e-10).
__global__ __launch_bounds__(256) void attn_mfma(
    const _Float16* __restrict__ q, const _Float16* __restrict__ k,
    const _Float16* __restrict__ eq, const _Float16* __restrict__ ek,
    const _Float16* __restrict__ mixedT, __bf16* __restrict__ ctx)
{
    const int h = blockIdx.y;
    const int q0 = blockIdx.x * 64;
    const int tid = threadIdx.x, lane = tid & 63, wv = tid >> 6;
    const int lo = lane & 15, hi = lane >> 4;
    const int hoff = h * HDIM;

    __shared__ _Float16 Kt[64 * 64];
    __shared__ _Float16 Et[64 * 64];
    __shared__ _Float16 Mt[64 * 64];
    __shared__ _Float16 Pt[4][64 * 18];    // per-wave [64key][16row+2pad]

    half8 qa[2], ea[2];
#pragma unroll
    for (int kk = 0; kk < 2; ++kk) {
        const int row = q0 + wv * 16 + lo;
        qa[kk] = *(const half8*)(q  + (size_t)row * DM + hoff + kk * 32 + hi * 8);
        ea[kk] = *(const half8*)(eq + (size_t)row * DM + hoff + kk * 32 + hi * 8);
    }

    f32x4 oacc[4];
    float mr[4], lr[4];
#pragma unroll
    for (int j = 0; j < 4; ++j) { mr[j] = 0.f; lr[j] = 0.f; }
#pragma unroll
    for (int n = 0; n < 4; ++n)
#pragma unroll
        for (int e = 0; e < 4; ++e) oacc[n][e] = 0.f;

    const int srow = tid >> 3, schk = tid & 7;
    const int sdst0 = srow * 64 + ((schk ^ (srow & 7)) << 3);
    const int sdst1 = (srow + 32) * 64 + ((schk ^ (srow & 7)) << 3);

    // band predicate for tile starting at kt_
    #define IN_BAND(kt_) ({ int _a = (kt_) - (q0 + 63); int _b = q0 - ((kt_) + 63); \
                            int _d = _a > 0 ? _a : (_b > 0 ? _b : 0); _d <= 160; })

    bool diagCur = IN_BAND(0);
    half8 rk0 = *(const half8*)(k  + (size_t)(srow) * DM + hoff + schk * 8);
    half8 rk1 = *(const half8*)(k  + (size_t)(srow + 32) * DM + hoff + schk * 8);
    half8 rm0 = *(const half8*)(mixedT + (size_t)(hoff + srow) * SEQ + schk * 8);
    half8 rm1 = *(const half8*)(mixedT + (size_t)(hoff + srow + 32) * SEQ + schk * 8);
    half8 re0, re1;
    if (diagCur) {
        re0 = *(const half8*)(ek + (size_t)(srow) * DM + hoff + schk * 8);
        re1 = *(const half8*)(ek + (size_t)(srow + 32) * DM + hoff + schk * 8);
    }

    for (int kt = 0; kt < SEQ; kt += 64) {
        __syncthreads();
        *(half8*)&Kt[sdst0] = rk0; *(half8*)&Kt[sdst1] = rk1;
        *(half8*)&Mt[sdst0] = rm0; *(half8*)&Mt[sdst1] = rm1;
        if (diagCur) { *(half8*)&Et[sdst0] = re0; *(half8*)&Et[sdst1] = re1; }
        __syncthreads();
        const bool diagNext = (kt + 64 < SEQ) && IN_BAND(kt + 64);
        if (kt + 64 < SEQ) {
            const int nt = kt + 64;
            rk0 = *(const half8*)(k  + (size_t)(nt + srow) * DM + hoff + schk * 8);
            rk1 = *(const half8*)(k  + (size_t)(nt + srow + 32) * DM + hoff + schk * 8);
            rm0 = *(const half8*)(mixedT + (size_t)(hoff + srow) * SEQ + nt + schk * 8);
            rm1 = *(const half8*)(mixedT + (size_t)(hoff + srow + 32) * SEQ + nt + schk * 8);
            if (diagNext) {
                re0 = *(const half8*)(ek + (size_t)(nt + srow) * DM + hoff + schk * 8);
                re1 = *(const half8*)(ek + (size_t)(nt + srow + 32) * DM + hoff + schk * 8);
            }
        }

        // ---- QK^T (always) and EQ*EK^T (band tiles only)
        f32x4 sa[4], se[4];
#pragma unroll
        for (int n = 0; n < 4; ++n)
#pragma unroll
            for (int e = 0; e < 4; ++e) { sa[n][e] = 0.f; se[n][e] = 0.f; }
#pragma unroll
        for (int kk = 0; kk < 2; ++kk)
#pragma unroll
            for (int nf = 0; nf < 4; ++nf) {
                const int rrow = lo + 16 * nf;
                const int coff = rrow * 64 + (((hi + 4 * kk) ^ (rrow & 7)) << 3);
                half8 kb = *(const half8*)&Kt[coff];
                sa[nf] = __builtin_amdgcn_mfma_f32_16x16x32_f16(qa[kk], kb, sa[nf], 0, 0, 0);
            }
        if (diagCur) {
#pragma unroll
            for (int kk = 0; kk < 2; ++kk)
#pragma unroll
                for (int nf = 0; nf < 4; ++nf) {
                    const int rrow = lo + 16 * nf;
                    const int coff = rrow * 64 + (((hi + 4 * kk) ^ (rrow & 7)) << 3);
                    half8 eb = *(const half8*)&Et[coff];
                    se[nf] = __builtin_amdgcn_mfma_f32_16x16x32_f16(ea[kk], eb, se[nf], 0, 0, 0);
                }
        }

        // ---- logits + defer-max check
        float lg[4][4];
        bool exc = false;
        const int qrow = q0 + wv * 16 + hi * 4;
        if (diagCur) {
#pragma unroll
            for (int nf = 0; nf < 4; ++nf) {
                const int key = kt + nf * 16 + lo;
#pragma unroll
                for (int j = 0; j < 4; ++j) {
                    int dd = qrow + j - key; dd = dd < 0 ? -dd : dd;
                    const float dec = exp2f(-0.14426950408889634f * (float)dd);
                    const float v = 0.125f * sa[nf][j] + 0.0625f * se[nf][j] * dec;
                    lg[nf][j] = v;
                    exc |= (v > mr[j] + 8.f);
                }
            }
        } else {
#pragma unroll
            for (int nf = 0; nf < 4; ++nf)
#pragma unroll
                for (int j = 0; j < 4; ++j) {
                    const float v = 0.125f * sa[nf][j];
                    lg[nf][j] = v;
                    exc |= (v > mr[j] + 8.f);
                }
        }
        if (__any((int)exc)) {                       // rare rescale path
#pragma unroll
            for (int j = 0; j < 4; ++j) {
                float tm = fmaxf(fmaxf(lg[0][j], lg[1][j]), fmaxf(lg[2][j], lg[3][j]));
#pragma unroll
                for (int off = 8; off >= 1; off >>= 1) tm = fmaxf(tm, __shfl_xor(tm, off));
                const float mnew = fmaxf(mr[j], tm);
                const float corr = __expf(mr[j] - mnew);
                lr[j] *= corr; mr[j] = mnew;
#pragma unroll
                for (int nfd = 0; nfd < 4; ++nfd) oacc[nfd][j] *= corr;
            }
        }
        // ---- P = exp(lg - m), lane-local l accumulation, P -> LDS (f16)
        _Float16* Pw = Pt[wv];
#pragma unroll
        for (int nf = 0; nf < 4; ++nf) {
            half4v pv;
#pragma unroll
            for (int j = 0; j < 4; ++j) {
                const float p = __expf(lg[nf][j] - mr[j]);
                lr[j] += p;
                pv[j] = (_Float16)p;
            }
            *(half4v*)&Pw[(lo + 16 * nf) * 18 + hi * 4] = pv;
        }
        __asm__ volatile("s_waitcnt lgkmcnt(0)" ::: "memory");

        // ---- PV: oacc += P * mixed
#pragma unroll
        for (int kk = 0; kk < 2; ++kk) {
            half8 mb[4];
#pragma unroll
            for (int nfd = 0; nfd < 4; ++nfd) {
                const int rrow = lo + 16 * nfd;
                mb[nfd] = *(const half8*)&Mt[rrow * 64 + (((hi + 4 * kk) ^ (rrow & 7)) << 3)];
            }
            half8 pa;
#pragma unroll
            for (int e = 0; e < 8; ++e)
                pa[e] = Pw[(kk * 32 + hi * 8 + e) * 18 + lo];
#pragma unroll
            for (int nfd = 0; nfd < 4; ++nfd)
                oacc[nfd] = __builtin_amdgcn_mfma_f32_16x16x32_f16(pa, mb[nfd], oacc[nfd], 0, 0, 0);
        }
        diagCur = diagNext;
    }
    #undef IN_BAND

    // ---- epilogue: reduce l over the 16-lane row group, normalize, store
#pragma unroll
    for (int j = 0; j < 4; ++j) {
#pragma unroll
        for (int off = 8; off >= 1; off >>= 1) lr[j] += __shfl_xor(lr[j], off);
    }
    const int qrow = q0 + wv * 16 + hi * 4;
#pragma unroll
    for (int nfd = 0; nfd < 4; ++nfd) {
        const int d = hoff + lo + 16 * nfd;
#pragma unroll
        for (int j = 0; j < 4; ++j)
            ctx[(size_t)(qrow + j) * DM + d] = (__bf16)(oacc[nfd][j] / lr[j]);
    }
}

// --------------------------------------------- layer norm, FP32 OUTPUT
__global__ __launch_bounds__(256) void lnorm_f32(
    const float* __restrict__ res, const float* __restrict__ g,
    const float* __restrict__ b, float* __restrict__ out)
{
    const int row = blockIdx.x, tid = threadIdx.x;
    const int wave = tid >> 6, lane = tid & 63;
    __shared__ float red[8];
    const float4 x = reinterpret_cast<const float4*>(res + (size_t)row * DM)[tid];
    float s  = x.x + x.y + x.z + x.w;
    float s2 = x.x * x.x + x.y * x.y + x.z * x.z + x.w * x.w;
#pragma unroll
    for (int off = 32; off >= 1; off >>= 1) {
        s  += __shfl_xor(s, off);
        s2 += __shfl_xor(s2, off);
    }
    if (lane == 0) { red[wave] = s; red[4 + wave] = s2; }
    __syncthreads();
    s  = red[0] + red[1] + red[2] + red[3];
    s2 = red[4] + red[5] + red[6] + red[7];
    const float mu  = s * (1.f / DM);
    const float var = s2 * (1.f / DM) - mu * mu;
    const float inv = rsqrtf(var + 1e-5f);
    const int col = tid * 4;
    float4 o;
    o.x = (x.x - mu) * inv * g[col + 0] + b[col + 0];
    o.y = (x.y - mu) * inv * g[col + 1] + b[col + 1];
    o.z = (x.z - mu) * inv * g[col + 2] + b[col + 2];
    o.w = (x.w - mu) * inv * g[col + 3] + b[col + 3];
    reinterpret_cast<float4*>(out + (size_t)row * DM)[tid] = o;
}

// ---------------------------------------------------------------- launch
// OUTPUT IS FP32. ws layout (~34.3 MB):
//   [0,4M)    hsb bf16        -> overlaid by mixedT f16 (hsb dead after g1)
//   [4,16M)   w0..w5 bf16 (Wq,Wk,Wv,Weq,Wek,Wo), 2MB each
//   [16,18M)  w6 = Wsup bf16
//   [18,22M)  qf f16   [22,26M) kf f16   } res f32 overlays [18,26M) post-attn
//   [26,30M)  eqf f16  [30,34M) ekf f16
//   [34M..)   cA (128K), sA (128K), bsup (4K)
// d_out staging: vb f16 [0,4M), supf f16 [4,8M); dead after mixT_fuse;
// ctx bf16 then occupies [0,4M); lnorm rewrites the full 8MB fp32 at the end.
extern "C" void kernel_launch(void* const* d_in, const int* in_sizes, int n_in,
                              void* d_out, int out_size, void* d_ws, size_t ws_size,
                              hipStream_t stream) {
    const float* hs   = (const float*)d_in[0];
    const float* Wq   = (const float*)d_in[1];
    const float* bq   = (const float*)d_in[2];
    const float* Wk   = (const float*)d_in[3];
    const float* bk   = (const float*)d_in[4];
    const float* Wv   = (const float*)d_in[5];
    const float* bv   = (const float*)d_in[6];
    const float* Wo   = (const float*)d_in[7];
    const float* bo   = (const float*)d_in[8];
    const float* Weq  = (const float*)d_in[9];
    const float* beq  = (const float*)d_in[10];
    const float* Wek  = (const float*)d_in[11];
    const float* bek  = (const float*)d_in[12];
    const float* ampw = (const float*)d_in[13];
    const float* ampb = (const float*)d_in[14];
    const float* phw  = (const float*)d_in[15];
    const float* phb  = (const float*)d_in[16];
    const float* mixw = (const float*)d_in[17];
    const float* mixb = (const float*)d_in[18];
    const float* lng  = (const float*)d_in[19];
    const float* lnb  = (const float*)d_in[20];
    float* out = (float*)d_out;

    static const int expect[21] = {
        2097152, 1048576, 1024, 1048576, 1024, 1048576, 1024, 1048576, 1024,
        1048576, 1024, 1048576, 1024, 16384, 16, 16384, 16, 65536, 1024,
        1024, 1024};
    bool ok = (n_in == 21) && (out_size == 2097152);
    if (ok) for (int i = 0; i < 21; ++i) ok = ok && (in_sizes[i] == expect[i]);
    if (!ok) {
        zero_out<<<(out_size + 255) / 256, 256, 0, stream>>>(out, out_size);
        return;
    }

    char* ws = (char*)d_ws;
    __bf16*   hsb = (__bf16*)ws;
    __bf16*   w0  = (__bf16*)(ws + (4  << 20));
    __bf16*   w1  = (__bf16*)(ws + (6  << 20));
    __bf16*   w2  = (__bf16*)(ws + (8  << 20));
    __bf16*   w3  = (__bf16*)(ws + (10 << 20));
    __bf16*   w4  = (__bf16*)(ws + (12 << 20));
    __bf16*   w5  = (__bf16*)(ws + (14 << 20));
    __bf16*   w6  = (__bf16*)(ws + (16 << 20));
    _Float16* qf  = (_Float16*)(ws + (18 << 20));
    _Float16* kf  = (_Float16*)(ws + (22 << 20));
    _Float16* eqf = (_Float16*)(ws + (26 << 20));
    _Float16* ekf = (_Float16*)(ws + (30 << 20));
    float*    cA  = (float*)(ws + (34 << 20));
    float*    sA  = cA + SEQ * NH;
    float*    bsup = sA + SEQ * NH;
    _Float16* mxT = (_Float16*)hsb;            // overlay: hsb dead after g1
    float*    res = (float*)(ws + (18 << 20)); // overlay: q/k dead after attn
    _Float16* vb   = (_Float16*)d_out;
    _Float16* supf = (_Float16*)((char*)d_out + (4 << 20));
    __bf16*   ctx  = (__bf16*)d_out;

    const int H8 = SEQ * DM / 8;
    cvt_bf16<<<(H8 + 255) / 256, 256, 0, stream>>>(hs, hsb, H8);

    CvtBatch cb;
    cb.src[0] = Wq;  cb.dst[0] = w0;
    cb.src[1] = Wk;  cb.dst[1] = w1;
    cb.src[2] = Wv;  cb.dst[2] = w2;
    cb.src[3] = Weq; cb.dst[3] = w3;
    cb.src[4] = Wek; cb.dst[4] = w4;
    cb.src[5] = Wo;  cb.dst[5] = w5;
    cvt_w6<<<dim3(512, 6), 256, 0, stream>>>(cb);

    wsup_k<<<1024, 256, 0, stream>>>(mixw, Wv, bv, mixb, w6, bsup);
    amp_fast<<<SEQ, 256, 0, stream>>>(hs, ampw, ampb, phw, phb, cA, sA);

    GemmBatch g1 = {};
    g1.A = hsb;
    g1.W[0] = w0; g1.bias[0] = bq;   g1.out[0] = qf;   g1.mode[0] = 3;
    g1.W[1] = w1; g1.bias[1] = bk;   g1.out[1] = kf;   g1.mode[1] = 3;
    g1.W[2] = w2; g1.bias[2] = bv;   g1.out[2] = vb;   g1.mode[2] = 3;
    g1.W[3] = w3; g1.bias[3] = beq;  g1.out[3] = eqf;  g1.mode[3] = 3;
    g1.W[4] = w4; g1.bias[4] = bek;  g1.out[4] = ekf;  g1.mode[4] = 3;
    g1.W[5] = w6; g1.bias[5] = bsup; g1.out[5] = supf; g1.mode[5] = 3;
    g1.resid = nullptr;
    gemm_bt<<<dim3(DM / 128, SEQ / 128, 6), 256, 0, stream>>>(g1);

    mixT_fuse<<<dim3(NH, SEQ / 32), 256, 0, stream>>>(vb, supf, cA, sA, mxT);

    attn_mfma<<<dim3(SEQ / 64, NH), 256, 0, stream>>>(qf, kf, eqf, ekf, mxT, ctx);

    GemmBatch g3 = {};
    g3.A = ctx;
    g3.W[0] = w5; g3.bias[0] = bo; g3.out[0] = res; g3.mode[0] = 2;
    g3.resid = hs;
    gemm_bt<<<dim3(DM / 128, SEQ / 128, 1), 256, 0, stream>>>(g3);

    lnorm_f32<<<SEQ, 256, 0, stream>>>(res, lng, lnb, out);
}